// Round 4
// baseline (1341.338 us; speedup 1.0000x reference)
//
#include <hip/hip_runtime.h>
#include <hip/hip_bf16.h>
#include <math.h>

// HEAT layer: K/Q/V GEMMs -> per-edge attention w/ segmented softmax (CSR + online softmax)
// -> output GEMM with sigmoid-skip mix. All f32 (correctness anchor) + ws_size guard.

#define NDIM 128

// ---------------- node GEMM: C[n,128] = A[n,128] @ W[128,128] + bias ----------------
// block 256 threads, tile 64 rows x 128 cols, BK=16
__global__ __launch_bounds__(256) void gemm_node(const float* __restrict__ A,
                                                 const float* __restrict__ W,
                                                 const float* __restrict__ bias,
                                                 float* __restrict__ C, int n)
{
    __shared__ float As[64][17];     // +1 pad
    __shared__ float Ws[16][128];
    const int tid = threadIdx.x;
    const int block_row = blockIdx.x * 64;
    const int colb = (tid & 31) * 4;
    const int rowb = (tid >> 5) * 8;

    float acc[8][4];
#pragma unroll
    for (int r = 0; r < 8; ++r)
#pragma unroll
        for (int c = 0; c < 4; ++c) acc[r][c] = 0.f;

    for (int k0 = 0; k0 < 128; k0 += 16) {
        // A tile: thread loads 4 floats. row = tid>>2 (0..63), seg = (tid&3)*4
        {
            const int r = tid >> 2, s = (tid & 3) * 4;
            const int gr = block_row + r;
            float4 av = make_float4(0.f, 0.f, 0.f, 0.f);
            if (gr < n) av = *(const float4*)(A + (size_t)gr * NDIM + k0 + s);
            As[r][s + 0] = av.x; As[r][s + 1] = av.y; As[r][s + 2] = av.z; As[r][s + 3] = av.w;
            // W tile 16x128: thread loads 2 float4
            const int kr = tid >> 5;
            const int kc = (tid & 31) * 4;
            *(float4*)&Ws[kr][kc]     = *(const float4*)(W + (size_t)(k0 + kr) * NDIM + kc);
            *(float4*)&Ws[kr + 8][kc] = *(const float4*)(W + (size_t)(k0 + kr + 8) * NDIM + kc);
        }
        __syncthreads();
#pragma unroll
        for (int kk = 0; kk < 16; ++kk) {
            const float4 w4 = *(const float4*)&Ws[kk][colb];
#pragma unroll
            for (int r = 0; r < 8; ++r) {
                const float a = As[rowb + r][kk];
                acc[r][0] += a * w4.x;
                acc[r][1] += a * w4.y;
                acc[r][2] += a * w4.z;
                acc[r][3] += a * w4.w;
            }
        }
        __syncthreads();
    }
    const float4 b4 = *(const float4*)(bias + colb);
#pragma unroll
    for (int r = 0; r < 8; ++r) {
        const int gr = block_row + rowb + r;
        if (gr < n) {
            float4 o = make_float4(acc[r][0] + b4.x, acc[r][1] + b4.y,
                                   acc[r][2] + b4.z, acc[r][3] + b4.w);
            *(float4*)(C + (size_t)gr * NDIM + colb) = o;
        }
    }
}

// ---------------- output GEMM: out = (agg @ Aw + Ab)*alpha + feat*(1-alpha) ----------------
template <bool AVG>
__global__ __launch_bounds__(256) void gemm_out(const float* __restrict__ A1,
                                                const float* __restrict__ A2,
                                                const float* __restrict__ W,
                                                const float* __restrict__ bias,
                                                const float* __restrict__ feat,
                                                const float* __restrict__ skip, int nid,
                                                float* __restrict__ C, int n)
{
    __shared__ float As[64][17];
    __shared__ float Ws[16][128];
    const int tid = threadIdx.x;
    const int block_row = blockIdx.x * 64;
    const int colb = (tid & 31) * 4;
    const int rowb = (tid >> 5) * 8;

    float acc[8][4];
#pragma unroll
    for (int r = 0; r < 8; ++r)
#pragma unroll
        for (int c = 0; c < 4; ++c) acc[r][c] = 0.f;

    for (int k0 = 0; k0 < 128; k0 += 16) {
        {
            const int r = tid >> 2, s = (tid & 3) * 4;
            const int gr = block_row + r;
            float4 av = make_float4(0.f, 0.f, 0.f, 0.f);
            if (gr < n) {
                av = *(const float4*)(A1 + (size_t)gr * NDIM + k0 + s);
                if (AVG) {
                    const float4 bv = *(const float4*)(A2 + (size_t)gr * NDIM + k0 + s);
                    av.x = 0.5f * (av.x + bv.x); av.y = 0.5f * (av.y + bv.y);
                    av.z = 0.5f * (av.z + bv.z); av.w = 0.5f * (av.w + bv.w);
                }
            }
            As[r][s + 0] = av.x; As[r][s + 1] = av.y; As[r][s + 2] = av.z; As[r][s + 3] = av.w;
            const int kr = tid >> 5;
            const int kc = (tid & 31) * 4;
            *(float4*)&Ws[kr][kc]     = *(const float4*)(W + (size_t)(k0 + kr) * NDIM + kc);
            *(float4*)&Ws[kr + 8][kc] = *(const float4*)(W + (size_t)(k0 + kr + 8) * NDIM + kc);
        }
        __syncthreads();
#pragma unroll
        for (int kk = 0; kk < 16; ++kk) {
            const float4 w4 = *(const float4*)&Ws[kk][colb];
#pragma unroll
            for (int r = 0; r < 8; ++r) {
                const float a = As[rowb + r][kk];
                acc[r][0] += a * w4.x;
                acc[r][1] += a * w4.y;
                acc[r][2] += a * w4.z;
                acc[r][3] += a * w4.w;
            }
        }
        __syncthreads();
    }
    const float sk = skip[nid];
    const float alpha = 1.f / (1.f + __expf(-sk));
    const float beta = 1.f - alpha;
    const float4 b4 = *(const float4*)(bias + colb);
#pragma unroll
    for (int r = 0; r < 8; ++r) {
        const int gr = block_row + rowb + r;
        if (gr < n) {
            const float4 f4 = *(const float4*)(feat + (size_t)gr * NDIM + colb);
            float4 o = make_float4((acc[r][0] + b4.x) * alpha + f4.x * beta,
                                   (acc[r][1] + b4.y) * alpha + f4.y * beta,
                                   (acc[r][2] + b4.z) * alpha + f4.z * beta,
                                   (acc[r][3] + b4.w) * alpha + f4.w * beta);
            *(float4*)(C + (size_t)gr * NDIM + colb) = o;
        }
    }
}

// ---------------- CSR build ----------------
__global__ void hist_kernel(const int* __restrict__ dst, int E, int* __restrict__ cnt)
{
    for (int i = blockIdx.x * blockDim.x + threadIdx.x; i < E; i += gridDim.x * blockDim.x)
        atomicAdd(&cnt[dst[i]], 1);
}

// one block of 1024 threads; cnt (in) -> off exclusive offsets; cnt overwritten with start offsets
__global__ __launch_bounds__(1024) void scan_kernel(int* __restrict__ cnt, int* __restrict__ off, int n)
{
    const int t = threadIdx.x;
    const int CH = (n + 1023) >> 10;
    const int b = t * CH;
    const int e = min(b + CH, n);
    int sum = 0;
    for (int i = b; i < e; ++i) sum += cnt[i];
    __shared__ int ps[1024];
    ps[t] = sum;
    __syncthreads();
    for (int o = 1; o < 1024; o <<= 1) {
        int v = (t >= o) ? ps[t - o] : 0;
        __syncthreads();
        ps[t] += v;
        __syncthreads();
    }
    int run = (t == 0) ? 0 : ps[t - 1];
    for (int i = b; i < e; ++i) {
        const int c = cnt[i];
        off[i] = run;
        cnt[i] = run;     // becomes scatter cursor start
        run += c;
    }
    if (t == 1023) off[n] = ps[1023];
}

__global__ void scatter_kernel(const int* __restrict__ dst, int E,
                               int* __restrict__ pos, int* __restrict__ eid)
{
    for (int i = blockIdx.x * blockDim.x + threadIdx.x; i < E; i += gridDim.x * blockDim.x) {
        const int d = dst[i];
        const int p = atomicAdd(&pos[d], 1);
        eid[p] = i;
    }
}

// ---------------- edge aggregation: one wave per dst, online softmax ----------------
// lane l: head h = l>>3, dims 2*(l&7), 2*(l&7)+1  => element index 2*l in the 128-row
__global__ __launch_bounds__(256) void edge_agg(const int* __restrict__ off,
                                                const int* __restrict__ eid,
                                                const int* __restrict__ src,
                                                const float* __restrict__ ev,
                                                const float* __restrict__ K,
                                                const float* __restrict__ Q,
                                                const float* __restrict__ V,
                                                const float* __restrict__ ew,
                                                const float* __restrict__ eb,
                                                float* __restrict__ agg, int n_dst)
{
    const int wid = (blockIdx.x * blockDim.x + threadIdx.x) >> 6;
    const int lane = threadIdx.x & 63;
    if (wid >= n_dst) return;
    const int beg = off[wid];
    const int end = off[wid + 1];
    const float ews = ew[0] * 0.25f;   // / sqrt(DK)=4
    const float ebs = eb[0] * 0.25f;
    const float2 q = *(const float2*)(Q + (size_t)wid * NDIM + 2 * lane);

    float m = -1e30f, z = 0.f;
    float ax = 0.f, ay = 0.f;
    for (int i = beg; i < end; ++i) {
        const int e = eid[i];
        const int s = src[e];
        const float f = ev[e] * ews + ebs;
        const float2 k2 = *(const float2*)(K + (size_t)s * NDIM + 2 * lane);
        const float2 v2 = *(const float2*)(V + (size_t)s * NDIM + 2 * lane);
        float prod = q.x * k2.x + q.y * k2.y;
        prod += __shfl_xor(prod, 1);
        prod += __shfl_xor(prod, 2);
        prod += __shfl_xor(prod, 4);
        const float sc = prod * f;
        const float mn = fmaxf(m, sc);
        const float c = __expf(m - mn);
        const float p = __expf(sc - mn);
        z = z * c + p;
        ax = ax * c + p * v2.x;
        ay = ay * c + p * v2.y;
        m = mn;
    }
    const float inv = (end > beg) ? 1.f / z : 0.f;
    float2 o; o.x = ax * inv; o.y = ay * inv;
    *(float2*)(agg + (size_t)wid * NDIM + 2 * lane) = o;
}

extern "C" void kernel_launch(void* const* d_in, const int* in_sizes, int n_in,
                              void* d_out, int out_size, void* d_ws, size_t ws_size,
                              hipStream_t stream)
{
    const float* feat0 = (const float*)d_in[0];
    const float* feat1 = (const float*)d_in[1];
    const float* ev0 = (const float*)d_in[2];
    const float* ev1 = (const float*)d_in[3];
    const float* ev2 = (const float*)d_in[4];
    const int* src0 = (const int*)d_in[5];
    const int* dst0 = (const int*)d_in[6];
    const int* src1 = (const int*)d_in[7];
    const int* dst1 = (const int*)d_in[8];
    const int* src2 = (const int*)d_in[9];
    const int* dst2 = (const int*)d_in[10];
    const float* Kw = (const float*)d_in[11];
    const float* Kb = (const float*)d_in[12];
    const float* Qw = (const float*)d_in[13];
    const float* Qb = (const float*)d_in[14];
    const float* Vw = (const float*)d_in[15];
    const float* Vb = (const float*)d_in[16];
    const float* Aw = (const float*)d_in[17];
    const float* Ab = (const float*)d_in[18];
    const float* ew = (const float*)d_in[19];
    const float* eb = (const float*)d_in[20];
    const float* skip = (const float*)d_in[21];

    const int n0 = in_sizes[0] / NDIM;
    const int n1 = in_sizes[1] / NDIM;
    const int E0 = in_sizes[5];
    const int E1 = in_sizes[7];
    const int E2 = in_sizes[9];

    // ---- workspace budget check (diagnostic guard: never write OOB) ----
    auto rup = [](size_t b) { return (b + 255) & ~size_t(255); };
    const size_t need =
        rup((size_t)n0 * NDIM * 4) * 3 +          // K0 Q0 V0
        rup((size_t)n1 * NDIM * 4) * 3 +          // K1 Q1 V1
        rup((size_t)n1 * NDIM * 4) +              // agg1
        rup((size_t)n0 * NDIM * 4) * 2 +          // agg0a agg0b
        rup((size_t)(n1 + 1) * 4) +
        rup((size_t)(n0 + 1) * 4) * 2 +
        rup((size_t)(n1 + n0 + n0) * 4) +
        rup((size_t)E0 * 4) + rup((size_t)E1 * 4) + rup((size_t)E2 * 4);
    if (ws_size < need) return;   // clean failure signature (absmax == max|ref|), no OOB

    // workspace bump allocator (256B aligned)
    char* p = (char*)d_ws;
    auto alloc = [&](size_t bytes) -> char* {
        char* r = p;
        p += (bytes + 255) & ~size_t(255);
        return r;
    };
    float* K0 = (float*)alloc((size_t)n0 * NDIM * 4);
    float* Q0 = (float*)alloc((size_t)n0 * NDIM * 4);
    float* V0 = (float*)alloc((size_t)n0 * NDIM * 4);
    float* K1 = (float*)alloc((size_t)n1 * NDIM * 4);
    float* Q1 = (float*)alloc((size_t)n1 * NDIM * 4);
    float* V1 = (float*)alloc((size_t)n1 * NDIM * 4);
    float* agg1  = (float*)alloc((size_t)n1 * NDIM * 4);
    float* agg0a = (float*)alloc((size_t)n0 * NDIM * 4);
    float* agg0b = (float*)alloc((size_t)n0 * NDIM * 4);
    int* off0 = (int*)alloc((size_t)(n1 + 1) * 4);
    int* off1 = (int*)alloc((size_t)(n0 + 1) * 4);
    int* off2 = (int*)alloc((size_t)(n0 + 1) * 4);
    int* posA = (int*)alloc((size_t)(n1 + n0 + n0) * 4);   // contiguous for one memset
    int* pos0 = posA;
    int* pos1 = posA + n1;
    int* pos2 = posA + n1 + n0;
    int* eid0 = (int*)alloc((size_t)E0 * 4);
    int* eid1 = (int*)alloc((size_t)E1 * 4);
    int* eid2 = (int*)alloc((size_t)E2 * 4);

    // ---- K/Q/V GEMMs ----
    const int W2 = NDIM * NDIM;
    dim3 blk(256);
    dim3 g0((n0 + 63) / 64), g1((n1 + 63) / 64);
    gemm_node<<<g0, blk, 0, stream>>>(feat0, Kw,       Kb,        K0, n0);
    gemm_node<<<g0, blk, 0, stream>>>(feat0, Qw,       Qb,        Q0, n0);
    gemm_node<<<g0, blk, 0, stream>>>(feat0, Vw,       Vb,        V0, n0);
    gemm_node<<<g1, blk, 0, stream>>>(feat1, Kw + W2,  Kb + NDIM, K1, n1);
    gemm_node<<<g1, blk, 0, stream>>>(feat1, Qw + W2,  Qb + NDIM, Q1, n1);
    gemm_node<<<g1, blk, 0, stream>>>(feat1, Vw + W2,  Vb + NDIM, V1, n1);

    // ---- CSR build ----
    hipMemsetAsync(posA, 0, (size_t)(n1 + n0 + n0) * 4, stream);
    hist_kernel<<<2048, 256, 0, stream>>>(dst0, E0, pos0);
    hist_kernel<<<2048, 256, 0, stream>>>(dst1, E1, pos1);
    hist_kernel<<<2048, 256, 0, stream>>>(dst2, E2, pos2);
    scan_kernel<<<1, 1024, 0, stream>>>(pos0, off0, n1);
    scan_kernel<<<1, 1024, 0, stream>>>(pos1, off1, n0);
    scan_kernel<<<1, 1024, 0, stream>>>(pos2, off2, n0);
    scatter_kernel<<<2048, 256, 0, stream>>>(dst0, E0, pos0, eid0);
    scatter_kernel<<<2048, 256, 0, stream>>>(dst1, E1, pos1, eid1);
    scatter_kernel<<<2048, 256, 0, stream>>>(dst2, E2, pos2, eid2);

    // ---- edge aggregation (one wave per dst) ----
    edge_agg<<<(n1 + 3) / 4, blk, 0, stream>>>(off0, eid0, src0, ev0, K0, Q1, V0, ew, eb, agg1, n1);
    edge_agg<<<(n0 + 3) / 4, blk, 0, stream>>>(off1, eid1, src1, ev1, K1, Q0, V1, ew, eb, agg0a, n0);
    edge_agg<<<(n0 + 3) / 4, blk, 0, stream>>>(off2, eid2, src2, ev2, K0, Q0, V0, ew, eb, agg0b, n0);

    // ---- output transform ----
    float* out = (float*)d_out;
    gemm_out<true ><<<g0, blk, 0, stream>>>(agg0a, agg0b, Aw,      Ab,        feat0, skip, 0, out, n0);
    gemm_out<false><<<g1, blk, 0, stream>>>(agg1,  nullptr, Aw + W2, Ab + NDIM, feat1, skip, 1, out + (size_t)n0 * NDIM, n1);
}

// Round 5
// 1094.730 us; speedup vs baseline: 1.2253x; 1.2253x over previous
//
#include <hip/hip_runtime.h>
#include <hip/hip_bf16.h>
#include <math.h>

// HEAT layer. Round 5: bf16 K/Q/V storage, CSR-permuted src/ev (no eid hop),
// software-pipelined edge loop. GEMMs still f32 vector compute.

#define NDIM 128

__device__ __forceinline__ float bf2f(unsigned short u) {
    union { unsigned int i; float f; } x; x.i = ((unsigned int)u) << 16; return x.f;
}
__device__ __forceinline__ unsigned short f2bf(float f) {
    unsigned int u = __float_as_uint(f);
    unsigned int r = (u + 0x7FFFu + ((u >> 16) & 1u)) >> 16;   // RNE
    return (unsigned short)r;
}

// ---------------- node GEMM: C[n,128](bf16) = A[n,128](f32) @ W[128,128] + bias ----------------
__global__ __launch_bounds__(256) void gemm_node(const float* __restrict__ A,
                                                 const float* __restrict__ W,
                                                 const float* __restrict__ bias,
                                                 unsigned short* __restrict__ C, int n)
{
    __shared__ float As[64][17];
    __shared__ float Ws[16][128];
    const int tid = threadIdx.x;
    const int block_row = blockIdx.x * 64;
    const int colb = (tid & 31) * 4;
    const int rowb = (tid >> 5) * 8;

    float acc[8][4];
#pragma unroll
    for (int r = 0; r < 8; ++r)
#pragma unroll
        for (int c = 0; c < 4; ++c) acc[r][c] = 0.f;

    for (int k0 = 0; k0 < 128; k0 += 16) {
        {
            const int r = tid >> 2, s = (tid & 3) * 4;
            const int gr = block_row + r;
            float4 av = make_float4(0.f, 0.f, 0.f, 0.f);
            if (gr < n) av = *(const float4*)(A + (size_t)gr * NDIM + k0 + s);
            As[r][s + 0] = av.x; As[r][s + 1] = av.y; As[r][s + 2] = av.z; As[r][s + 3] = av.w;
            const int kr = tid >> 5;
            const int kc = (tid & 31) * 4;
            *(float4*)&Ws[kr][kc]     = *(const float4*)(W + (size_t)(k0 + kr) * NDIM + kc);
            *(float4*)&Ws[kr + 8][kc] = *(const float4*)(W + (size_t)(k0 + kr + 8) * NDIM + kc);
        }
        __syncthreads();
#pragma unroll
        for (int kk = 0; kk < 16; ++kk) {
            const float4 w4 = *(const float4*)&Ws[kk][colb];
#pragma unroll
            for (int r = 0; r < 8; ++r) {
                const float a = As[rowb + r][kk];
                acc[r][0] += a * w4.x;
                acc[r][1] += a * w4.y;
                acc[r][2] += a * w4.z;
                acc[r][3] += a * w4.w;
            }
        }
        __syncthreads();
    }
    const float4 b4 = *(const float4*)(bias + colb);
#pragma unroll
    for (int r = 0; r < 8; ++r) {
        const int gr = block_row + rowb + r;
        if (gr < n) {
            ushort4 o;
            o.x = f2bf(acc[r][0] + b4.x);
            o.y = f2bf(acc[r][1] + b4.y);
            o.z = f2bf(acc[r][2] + b4.z);
            o.w = f2bf(acc[r][3] + b4.w);
            *(ushort4*)(C + (size_t)gr * NDIM + colb) = o;
        }
    }
}

// ---------------- output GEMM: out = (agg @ Aw + Ab)*alpha + feat*(1-alpha) ----------------
template <bool AVG>
__global__ __launch_bounds__(256) void gemm_out(const float* __restrict__ A1,
                                                const float* __restrict__ A2,
                                                const float* __restrict__ W,
                                                const float* __restrict__ bias,
                                                const float* __restrict__ feat,
                                                const float* __restrict__ skip, int nid,
                                                float* __restrict__ C, int n)
{
    __shared__ float As[64][17];
    __shared__ float Ws[16][128];
    const int tid = threadIdx.x;
    const int block_row = blockIdx.x * 64;
    const int colb = (tid & 31) * 4;
    const int rowb = (tid >> 5) * 8;

    float acc[8][4];
#pragma unroll
    for (int r = 0; r < 8; ++r)
#pragma unroll
        for (int c = 0; c < 4; ++c) acc[r][c] = 0.f;

    for (int k0 = 0; k0 < 128; k0 += 16) {
        {
            const int r = tid >> 2, s = (tid & 3) * 4;
            const int gr = block_row + r;
            float4 av = make_float4(0.f, 0.f, 0.f, 0.f);
            if (gr < n) {
                av = *(const float4*)(A1 + (size_t)gr * NDIM + k0 + s);
                if (AVG) {
                    const float4 bv = *(const float4*)(A2 + (size_t)gr * NDIM + k0 + s);
                    av.x = 0.5f * (av.x + bv.x); av.y = 0.5f * (av.y + bv.y);
                    av.z = 0.5f * (av.z + bv.z); av.w = 0.5f * (av.w + bv.w);
                }
            }
            As[r][s + 0] = av.x; As[r][s + 1] = av.y; As[r][s + 2] = av.z; As[r][s + 3] = av.w;
            const int kr = tid >> 5;
            const int kc = (tid & 31) * 4;
            *(float4*)&Ws[kr][kc]     = *(const float4*)(W + (size_t)(k0 + kr) * NDIM + kc);
            *(float4*)&Ws[kr + 8][kc] = *(const float4*)(W + (size_t)(k0 + kr + 8) * NDIM + kc);
        }
        __syncthreads();
#pragma unroll
        for (int kk = 0; kk < 16; ++kk) {
            const float4 w4 = *(const float4*)&Ws[kk][colb];
#pragma unroll
            for (int r = 0; r < 8; ++r) {
                const float a = As[rowb + r][kk];
                acc[r][0] += a * w4.x;
                acc[r][1] += a * w4.y;
                acc[r][2] += a * w4.z;
                acc[r][3] += a * w4.w;
            }
        }
        __syncthreads();
    }
    const float sk = skip[nid];
    const float alpha = 1.f / (1.f + __expf(-sk));
    const float beta = 1.f - alpha;
    const float4 b4 = *(const float4*)(bias + colb);
#pragma unroll
    for (int r = 0; r < 8; ++r) {
        const int gr = block_row + rowb + r;
        if (gr < n) {
            const float4 f4 = *(const float4*)(feat + (size_t)gr * NDIM + colb);
            float4 o = make_float4((acc[r][0] + b4.x) * alpha + f4.x * beta,
                                   (acc[r][1] + b4.y) * alpha + f4.y * beta,
                                   (acc[r][2] + b4.z) * alpha + f4.z * beta,
                                   (acc[r][3] + b4.w) * alpha + f4.w * beta);
            *(float4*)(C + (size_t)gr * NDIM + colb) = o;
        }
    }
}

// ---------------- CSR build ----------------
__global__ void hist_kernel(const int* __restrict__ dst, int E, int* __restrict__ cnt)
{
    for (int i = blockIdx.x * blockDim.x + threadIdx.x; i < E; i += gridDim.x * blockDim.x)
        atomicAdd(&cnt[dst[i]], 1);
}

__global__ __launch_bounds__(1024) void scan_kernel(int* __restrict__ cnt, int* __restrict__ off, int n)
{
    const int t = threadIdx.x;
    const int CH = (n + 1023) >> 10;
    const int b = t * CH;
    const int e = min(b + CH, n);
    int sum = 0;
    for (int i = b; i < e; ++i) sum += cnt[i];
    __shared__ int ps[1024];
    ps[t] = sum;
    __syncthreads();
    for (int o = 1; o < 1024; o <<= 1) {
        int v = (t >= o) ? ps[t - o] : 0;
        __syncthreads();
        ps[t] += v;
        __syncthreads();
    }
    int run = (t == 0) ? 0 : ps[t - 1];
    for (int i = b; i < e; ++i) {
        const int c = cnt[i];
        off[i] = run;
        cnt[i] = run;
        run += c;
    }
    if (t == 1023) off[n] = ps[1023];
}

// permute src & ev into CSR order (kills the eid indirection in edge_agg)
__global__ void scatter_kernel(const int* __restrict__ dst, const int* __restrict__ src,
                               const float* __restrict__ ev, int E,
                               int* __restrict__ pos,
                               int* __restrict__ srcs_p, float* __restrict__ evs_p)
{
    for (int i = blockIdx.x * blockDim.x + threadIdx.x; i < E; i += gridDim.x * blockDim.x) {
        const int d = dst[i];
        const int p = atomicAdd(&pos[d], 1);
        srcs_p[p] = src[i];
        evs_p[p] = ev[i];
    }
}

// ---------------- edge aggregation: one wave per dst, online softmax, pipelined ----------------
// lane l: head h = l>>3, dims 2*(l&7), 2*(l&7)+1 => element index 2*l in the 128-row
__global__ __launch_bounds__(256) void edge_agg(const int* __restrict__ off,
                                                const int* __restrict__ srcs,
                                                const float* __restrict__ evs,
                                                const unsigned short* __restrict__ K,
                                                const unsigned short* __restrict__ Q,
                                                const unsigned short* __restrict__ V,
                                                const float* __restrict__ ew,
                                                const float* __restrict__ eb,
                                                float* __restrict__ agg, int n_dst)
{
    const int wid = (blockIdx.x * blockDim.x + threadIdx.x) >> 6;
    const int lane = threadIdx.x & 63;
    if (wid >= n_dst) return;
    const int beg = off[wid];
    const int end = off[wid + 1];
    const float ews = ew[0] * 0.25f;   // / sqrt(DK)=4
    const float ebs = eb[0] * 0.25f;
    const ushort2 qr = *(const ushort2*)(Q + (size_t)wid * NDIM + 2 * lane);
    const float qx = bf2f(qr.x), qy = bf2f(qr.y);

    float m = -1e30f, z = 0.f;
    float ax = 0.f, ay = 0.f;

    // 2-deep index pipeline: K/V gather for edge i issues with its index already resident
    int s0 = 0, s1 = 0;
    float f0 = 0.f, f1 = 0.f;
    if (beg < end)     { s0 = srcs[beg];     f0 = evs[beg]; }
    if (beg + 1 < end) { s1 = srcs[beg + 1]; f1 = evs[beg + 1]; }

    for (int i = beg; i < end; ++i) {
        const ushort2 kr = *(const ushort2*)(K + (size_t)s0 * NDIM + 2 * lane);
        const ushort2 vr = *(const ushort2*)(V + (size_t)s0 * NDIM + 2 * lane);
        int s2 = 0; float f2 = 0.f;
        if (i + 2 < end) { s2 = srcs[i + 2]; f2 = evs[i + 2]; }
        const float f = f0 * ews + ebs;

        float prod = qx * bf2f(kr.x) + qy * bf2f(kr.y);
        prod += __shfl_xor(prod, 1);
        prod += __shfl_xor(prod, 2);
        prod += __shfl_xor(prod, 4);
        const float sc = prod * f;
        const float mn = fmaxf(m, sc);
        const float c = __expf(m - mn);
        const float p = __expf(sc - mn);
        z = z * c + p;
        ax = ax * c + p * bf2f(vr.x);
        ay = ay * c + p * bf2f(vr.y);
        m = mn;

        s0 = s1; f0 = f1; s1 = s2; f1 = f2;
    }
    const float inv = (end > beg) ? 1.f / z : 0.f;
    float2 o; o.x = ax * inv; o.y = ay * inv;
    *(float2*)(agg + (size_t)wid * NDIM + 2 * lane) = o;
}

extern "C" void kernel_launch(void* const* d_in, const int* in_sizes, int n_in,
                              void* d_out, int out_size, void* d_ws, size_t ws_size,
                              hipStream_t stream)
{
    const float* feat0 = (const float*)d_in[0];
    const float* feat1 = (const float*)d_in[1];
    const float* ev0 = (const float*)d_in[2];
    const float* ev1 = (const float*)d_in[3];
    const float* ev2 = (const float*)d_in[4];
    const int* src0 = (const int*)d_in[5];
    const int* dst0 = (const int*)d_in[6];
    const int* src1 = (const int*)d_in[7];
    const int* dst1 = (const int*)d_in[8];
    const int* src2 = (const int*)d_in[9];
    const int* dst2 = (const int*)d_in[10];
    const float* Kw = (const float*)d_in[11];
    const float* Kb = (const float*)d_in[12];
    const float* Qw = (const float*)d_in[13];
    const float* Qb = (const float*)d_in[14];
    const float* Vw = (const float*)d_in[15];
    const float* Vb = (const float*)d_in[16];
    const float* Aw = (const float*)d_in[17];
    const float* Ab = (const float*)d_in[18];
    const float* ew = (const float*)d_in[19];
    const float* eb = (const float*)d_in[20];
    const float* skip = (const float*)d_in[21];

    const int n0 = in_sizes[0] / NDIM;
    const int n1 = in_sizes[1] / NDIM;
    const int E0 = in_sizes[5];
    const int E1 = in_sizes[7];
    const int E2 = in_sizes[9];

    auto rup = [](size_t b) { return (b + 255) & ~size_t(255); };
    const size_t need =
        rup((size_t)n0 * NDIM * 2) * 3 +          // K0 Q0 V0 (bf16)
        rup((size_t)n1 * NDIM * 2) * 3 +          // K1 Q1 V1 (bf16)
        rup((size_t)n1 * NDIM * 4) +              // agg1
        rup((size_t)n0 * NDIM * 4) * 2 +          // agg0a agg0b
        rup((size_t)(n1 + 1) * 4) +
        rup((size_t)(n0 + 1) * 4) * 2 +
        rup((size_t)(n1 + n0 + n0) * 4) +
        (rup((size_t)E0 * 4) + rup((size_t)E1 * 4) + rup((size_t)E2 * 4)) * 2;
    if (ws_size < need) return;

    char* p = (char*)d_ws;
    auto alloc = [&](size_t bytes) -> char* {
        char* r = p;
        p += (bytes + 255) & ~size_t(255);
        return r;
    };
    unsigned short* K0 = (unsigned short*)alloc((size_t)n0 * NDIM * 2);
    unsigned short* Q0 = (unsigned short*)alloc((size_t)n0 * NDIM * 2);
    unsigned short* V0 = (unsigned short*)alloc((size_t)n0 * NDIM * 2);
    unsigned short* K1 = (unsigned short*)alloc((size_t)n1 * NDIM * 2);
    unsigned short* Q1 = (unsigned short*)alloc((size_t)n1 * NDIM * 2);
    unsigned short* V1 = (unsigned short*)alloc((size_t)n1 * NDIM * 2);
    float* agg1  = (float*)alloc((size_t)n1 * NDIM * 4);
    float* agg0a = (float*)alloc((size_t)n0 * NDIM * 4);
    float* agg0b = (float*)alloc((size_t)n0 * NDIM * 4);
    int* off0 = (int*)alloc((size_t)(n1 + 1) * 4);
    int* off1 = (int*)alloc((size_t)(n0 + 1) * 4);
    int* off2 = (int*)alloc((size_t)(n0 + 1) * 4);
    int* posA = (int*)alloc((size_t)(n1 + n0 + n0) * 4);
    int* pos0 = posA;
    int* pos1 = posA + n1;
    int* pos2 = posA + n1 + n0;
    int*   srcs0 = (int*)alloc((size_t)E0 * 4);
    float* evs0  = (float*)alloc((size_t)E0 * 4);
    int*   srcs1 = (int*)alloc((size_t)E1 * 4);
    float* evs1  = (float*)alloc((size_t)E1 * 4);
    int*   srcs2 = (int*)alloc((size_t)E2 * 4);
    float* evs2  = (float*)alloc((size_t)E2 * 4);

    const int W2 = NDIM * NDIM;
    dim3 blk(256);
    dim3 g0((n0 + 63) / 64), g1((n1 + 63) / 64);
    gemm_node<<<g0, blk, 0, stream>>>(feat0, Kw,       Kb,        K0, n0);
    gemm_node<<<g0, blk, 0, stream>>>(feat0, Qw,       Qb,        Q0, n0);
    gemm_node<<<g0, blk, 0, stream>>>(feat0, Vw,       Vb,        V0, n0);
    gemm_node<<<g1, blk, 0, stream>>>(feat1, Kw + W2,  Kb + NDIM, K1, n1);
    gemm_node<<<g1, blk, 0, stream>>>(feat1, Qw + W2,  Qb + NDIM, Q1, n1);
    gemm_node<<<g1, blk, 0, stream>>>(feat1, Vw + W2,  Vb + NDIM, V1, n1);

    hipMemsetAsync(posA, 0, (size_t)(n1 + n0 + n0) * 4, stream);
    hist_kernel<<<2048, 256, 0, stream>>>(dst0, E0, pos0);
    hist_kernel<<<2048, 256, 0, stream>>>(dst1, E1, pos1);
    hist_kernel<<<2048, 256, 0, stream>>>(dst2, E2, pos2);
    scan_kernel<<<1, 1024, 0, stream>>>(pos0, off0, n1);
    scan_kernel<<<1, 1024, 0, stream>>>(pos1, off1, n0);
    scan_kernel<<<1, 1024, 0, stream>>>(pos2, off2, n0);
    scatter_kernel<<<2048, 256, 0, stream>>>(dst0, src0, ev0, E0, pos0, srcs0, evs0);
    scatter_kernel<<<2048, 256, 0, stream>>>(dst1, src1, ev1, E1, pos1, srcs1, evs1);
    scatter_kernel<<<2048, 256, 0, stream>>>(dst2, src2, ev2, E2, pos2, srcs2, evs2);

    edge_agg<<<(n1 + 3) / 4, blk, 0, stream>>>(off0, srcs0, evs0, K0, Q1, V0, ew, eb, agg1, n1);
    edge_agg<<<(n0 + 3) / 4, blk, 0, stream>>>(off1, srcs1, evs1, K1, Q0, V1, ew, eb, agg0a, n0);
    edge_agg<<<(n0 + 3) / 4, blk, 0, stream>>>(off2, srcs2, evs2, K0, Q0, V0, ew, eb, agg0b, n0);

    float* out = (float*)d_out;
    gemm_out<true ><<<g0, blk, 0, stream>>>(agg0a, agg0b, Aw,      Ab,        feat0, skip, 0, out, n0);
    gemm_out<false><<<g1, blk, 0, stream>>>(agg1,  nullptr, Aw + W2, Ab + NDIM, feat1, skip, 1, out + (size_t)n0 * NDIM, n1);
}

// Round 6
// 782.919 us; speedup vs baseline: 1.7133x; 1.3983x over previous
//
#include <hip/hip_runtime.h>
#include <hip/hip_bf16.h>
#include <math.h>

// HEAT layer. Round 6: replace single-block scans (3x110us) with parallel
// 3-phase segmented scan (~16us). Everything else identical to round 5.

#define NDIM 128
#define SCH 2048      // elements per scan block (256 thr x 8)
#define MAXNB 64      // max scan blocks per segment (supports n <= 131072)

__device__ __forceinline__ float bf2f(unsigned short u) {
    union { unsigned int i; float f; } x; x.i = ((unsigned int)u) << 16; return x.f;
}
__device__ __forceinline__ unsigned short f2bf(float f) {
    unsigned int u = __float_as_uint(f);
    unsigned int r = (u + 0x7FFFu + ((u >> 16) & 1u)) >> 16;   // RNE
    return (unsigned short)r;
}

// ---------------- node GEMM: C[n,128](bf16) = A[n,128](f32) @ W[128,128] + bias ----------------
__global__ __launch_bounds__(256) void gemm_node(const float* __restrict__ A,
                                                 const float* __restrict__ W,
                                                 const float* __restrict__ bias,
                                                 unsigned short* __restrict__ C, int n)
{
    __shared__ float As[64][17];
    __shared__ float Ws[16][128];
    const int tid = threadIdx.x;
    const int block_row = blockIdx.x * 64;
    const int colb = (tid & 31) * 4;
    const int rowb = (tid >> 5) * 8;

    float acc[8][4];
#pragma unroll
    for (int r = 0; r < 8; ++r)
#pragma unroll
        for (int c = 0; c < 4; ++c) acc[r][c] = 0.f;

    for (int k0 = 0; k0 < 128; k0 += 16) {
        {
            const int r = tid >> 2, s = (tid & 3) * 4;
            const int gr = block_row + r;
            float4 av = make_float4(0.f, 0.f, 0.f, 0.f);
            if (gr < n) av = *(const float4*)(A + (size_t)gr * NDIM + k0 + s);
            As[r][s + 0] = av.x; As[r][s + 1] = av.y; As[r][s + 2] = av.z; As[r][s + 3] = av.w;
            const int kr = tid >> 5;
            const int kc = (tid & 31) * 4;
            *(float4*)&Ws[kr][kc]     = *(const float4*)(W + (size_t)(k0 + kr) * NDIM + kc);
            *(float4*)&Ws[kr + 8][kc] = *(const float4*)(W + (size_t)(k0 + kr + 8) * NDIM + kc);
        }
        __syncthreads();
#pragma unroll
        for (int kk = 0; kk < 16; ++kk) {
            const float4 w4 = *(const float4*)&Ws[kk][colb];
#pragma unroll
            for (int r = 0; r < 8; ++r) {
                const float a = As[rowb + r][kk];
                acc[r][0] += a * w4.x;
                acc[r][1] += a * w4.y;
                acc[r][2] += a * w4.z;
                acc[r][3] += a * w4.w;
            }
        }
        __syncthreads();
    }
    const float4 b4 = *(const float4*)(bias + colb);
#pragma unroll
    for (int r = 0; r < 8; ++r) {
        const int gr = block_row + rowb + r;
        if (gr < n) {
            ushort4 o;
            o.x = f2bf(acc[r][0] + b4.x);
            o.y = f2bf(acc[r][1] + b4.y);
            o.z = f2bf(acc[r][2] + b4.z);
            o.w = f2bf(acc[r][3] + b4.w);
            *(ushort4*)(C + (size_t)gr * NDIM + colb) = o;
        }
    }
}

// ---------------- output GEMM: out = (agg @ Aw + Ab)*alpha + feat*(1-alpha) ----------------
template <bool AVG>
__global__ __launch_bounds__(256) void gemm_out(const float* __restrict__ A1,
                                                const float* __restrict__ A2,
                                                const float* __restrict__ W,
                                                const float* __restrict__ bias,
                                                const float* __restrict__ feat,
                                                const float* __restrict__ skip, int nid,
                                                float* __restrict__ C, int n)
{
    __shared__ float As[64][17];
    __shared__ float Ws[16][128];
    const int tid = threadIdx.x;
    const int block_row = blockIdx.x * 64;
    const int colb = (tid & 31) * 4;
    const int rowb = (tid >> 5) * 8;

    float acc[8][4];
#pragma unroll
    for (int r = 0; r < 8; ++r)
#pragma unroll
        for (int c = 0; c < 4; ++c) acc[r][c] = 0.f;

    for (int k0 = 0; k0 < 128; k0 += 16) {
        {
            const int r = tid >> 2, s = (tid & 3) * 4;
            const int gr = block_row + r;
            float4 av = make_float4(0.f, 0.f, 0.f, 0.f);
            if (gr < n) {
                av = *(const float4*)(A1 + (size_t)gr * NDIM + k0 + s);
                if (AVG) {
                    const float4 bv = *(const float4*)(A2 + (size_t)gr * NDIM + k0 + s);
                    av.x = 0.5f * (av.x + bv.x); av.y = 0.5f * (av.y + bv.y);
                    av.z = 0.5f * (av.z + bv.z); av.w = 0.5f * (av.w + bv.w);
                }
            }
            As[r][s + 0] = av.x; As[r][s + 1] = av.y; As[r][s + 2] = av.z; As[r][s + 3] = av.w;
            const int kr = tid >> 5;
            const int kc = (tid & 31) * 4;
            *(float4*)&Ws[kr][kc]     = *(const float4*)(W + (size_t)(k0 + kr) * NDIM + kc);
            *(float4*)&Ws[kr + 8][kc] = *(const float4*)(W + (size_t)(k0 + kr + 8) * NDIM + kc);
        }
        __syncthreads();
#pragma unroll
        for (int kk = 0; kk < 16; ++kk) {
            const float4 w4 = *(const float4*)&Ws[kk][colb];
#pragma unroll
            for (int r = 0; r < 8; ++r) {
                const float a = As[rowb + r][kk];
                acc[r][0] += a * w4.x;
                acc[r][1] += a * w4.y;
                acc[r][2] += a * w4.z;
                acc[r][3] += a * w4.w;
            }
        }
        __syncthreads();
    }
    const float sk = skip[nid];
    const float alpha = 1.f / (1.f + __expf(-sk));
    const float beta = 1.f - alpha;
    const float4 b4 = *(const float4*)(bias + colb);
#pragma unroll
    for (int r = 0; r < 8; ++r) {
        const int gr = block_row + rowb + r;
        if (gr < n) {
            const float4 f4 = *(const float4*)(feat + (size_t)gr * NDIM + colb);
            float4 o = make_float4((acc[r][0] + b4.x) * alpha + f4.x * beta,
                                   (acc[r][1] + b4.y) * alpha + f4.y * beta,
                                   (acc[r][2] + b4.z) * alpha + f4.z * beta,
                                   (acc[r][3] + b4.w) * alpha + f4.w * beta);
            *(float4*)(C + (size_t)gr * NDIM + colb) = o;
        }
    }
}

// ---------------- CSR build ----------------
__global__ void hist_kernel(const int* __restrict__ dst, int E, int* __restrict__ cnt)
{
    for (int i = blockIdx.x * blockDim.x + threadIdx.x; i < E; i += gridDim.x * blockDim.x)
        atomicAdd(&cnt[dst[i]], 1);
}

// ---- 3-phase parallel scan over 3 independent segments (grid.y = segment) ----
// Phase A: per-block partial sums of 2048-element chunks
__global__ __launch_bounds__(256) void scan_partial(
    const int* __restrict__ c0, int nA, const int* __restrict__ c1, int nB,
    const int* __restrict__ c2, int nC, int* __restrict__ partial)
{
    const int seg = blockIdx.y;
    const int* c = seg == 0 ? c0 : (seg == 1 ? c1 : c2);
    const int n = seg == 0 ? nA : (seg == 1 ? nB : nC);
    const int beg = blockIdx.x * SCH;
    const int t = threadIdx.x;
    int s = 0;
    if (beg < n) {
        const int base_i = beg + t * 8;
#pragma unroll
        for (int j = 0; j < 8; ++j) {
            const int i = base_i + j;
            if (i < n) s += c[i];
        }
    }
#pragma unroll
    for (int o = 1; o < 64; o <<= 1) s += __shfl_xor(s, o);
    __shared__ int ws[4];
    const int lane = t & 63, w = t >> 6;
    if (lane == 0) ws[w] = s;
    __syncthreads();
    if (t == 0) partial[seg * MAXNB + blockIdx.x] = ws[0] + ws[1] + ws[2] + ws[3];
}

// Phase B: exclusive-scan the partials per segment (3 independent threads), write off[n]
__global__ void scan_base(int* __restrict__ partial, int nA, int nB, int nC,
                          int* __restrict__ offA, int* __restrict__ offB, int* __restrict__ offC)
{
    const int seg = threadIdx.x;
    if (seg >= 3) return;
    const int n = seg == 0 ? nA : (seg == 1 ? nB : nC);
    int* off = seg == 0 ? offA : (seg == 1 ? offB : offC);
    const int nb = (n + SCH - 1) / SCH;
    int run = 0;
    for (int b = 0; b < nb; ++b) {
        const int v = partial[seg * MAXNB + b];
        partial[seg * MAXNB + b] = run;
        run += v;
    }
    off[n] = run;
}

// Phase C: block-local exclusive scan + global base; writes off[] and cursor (cnt in place)
__global__ __launch_bounds__(256) void scan_final(
    int* __restrict__ c0, int nA, int* __restrict__ offA,
    int* __restrict__ c1, int nB, int* __restrict__ offB,
    int* __restrict__ c2, int nC, int* __restrict__ offC,
    const int* __restrict__ partial)
{
    const int seg = blockIdx.y;
    int* c = seg == 0 ? c0 : (seg == 1 ? c1 : c2);
    int* off = seg == 0 ? offA : (seg == 1 ? offB : offC);
    const int n = seg == 0 ? nA : (seg == 1 ? nB : nC);
    const int beg = blockIdx.x * SCH;
    if (beg >= n) return;
    const int t = threadIdx.x, lane = t & 63, w = t >> 6;
    const int base_i = beg + t * 8;

    int v[8];
    int run = 0;
#pragma unroll
    for (int j = 0; j < 8; ++j) {
        const int i = base_i + j;
        const int x = (i < n) ? c[i] : 0;
        v[j] = run;          // exclusive-local prefix
        run += x;
    }
    const int tsum = run;
    // wave inclusive scan of tsum
    int x = tsum;
#pragma unroll
    for (int o = 1; o < 64; o <<= 1) {
        const int y = __shfl_up(x, o);
        if (lane >= o) x += y;
    }
    const int wexc = x - tsum;   // exclusive within wave
    __shared__ int wsum[4];
    if (lane == 63) wsum[w] = x; // wave total
    __syncthreads();
    int wbase = 0;
    for (int i = 0; i < w; ++i) wbase += wsum[i];
    const int base = partial[seg * MAXNB + blockIdx.x] + wbase + wexc;
#pragma unroll
    for (int j = 0; j < 8; ++j) {
        const int i = base_i + j;
        if (i < n) {
            const int e = base + v[j];
            off[i] = e;
            c[i] = e;        // scatter cursor start
        }
    }
}

// permute src & ev into CSR order (kills the eid indirection in edge_agg)
__global__ void scatter_kernel(const int* __restrict__ dst, const int* __restrict__ src,
                               const float* __restrict__ ev, int E,
                               int* __restrict__ pos,
                               int* __restrict__ srcs_p, float* __restrict__ evs_p)
{
    for (int i = blockIdx.x * blockDim.x + threadIdx.x; i < E; i += gridDim.x * blockDim.x) {
        const int d = dst[i];
        const int p = atomicAdd(&pos[d], 1);
        srcs_p[p] = src[i];
        evs_p[p] = ev[i];
    }
}

// ---------------- edge aggregation: one wave per dst, online softmax, pipelined ----------------
__global__ __launch_bounds__(256) void edge_agg(const int* __restrict__ off,
                                                const int* __restrict__ srcs,
                                                const float* __restrict__ evs,
                                                const unsigned short* __restrict__ K,
                                                const unsigned short* __restrict__ Q,
                                                const unsigned short* __restrict__ V,
                                                const float* __restrict__ ew,
                                                const float* __restrict__ eb,
                                                float* __restrict__ agg, int n_dst)
{
    const int wid = (blockIdx.x * blockDim.x + threadIdx.x) >> 6;
    const int lane = threadIdx.x & 63;
    if (wid >= n_dst) return;
    const int beg = off[wid];
    const int end = off[wid + 1];
    const float ews = ew[0] * 0.25f;   // / sqrt(DK)=4
    const float ebs = eb[0] * 0.25f;
    const ushort2 qr = *(const ushort2*)(Q + (size_t)wid * NDIM + 2 * lane);
    const float qx = bf2f(qr.x), qy = bf2f(qr.y);

    float m = -1e30f, z = 0.f;
    float ax = 0.f, ay = 0.f;

    int s0 = 0, s1 = 0;
    float f0 = 0.f, f1 = 0.f;
    if (beg < end)     { s0 = srcs[beg];     f0 = evs[beg]; }
    if (beg + 1 < end) { s1 = srcs[beg + 1]; f1 = evs[beg + 1]; }

    for (int i = beg; i < end; ++i) {
        const ushort2 kr = *(const ushort2*)(K + (size_t)s0 * NDIM + 2 * lane);
        const ushort2 vr = *(const ushort2*)(V + (size_t)s0 * NDIM + 2 * lane);
        int s2 = 0; float f2 = 0.f;
        if (i + 2 < end) { s2 = srcs[i + 2]; f2 = evs[i + 2]; }
        const float f = f0 * ews + ebs;

        float prod = qx * bf2f(kr.x) + qy * bf2f(kr.y);
        prod += __shfl_xor(prod, 1);
        prod += __shfl_xor(prod, 2);
        prod += __shfl_xor(prod, 4);
        const float sc = prod * f;
        const float mn = fmaxf(m, sc);
        const float c = __expf(m - mn);
        const float p = __expf(sc - mn);
        z = z * c + p;
        ax = ax * c + p * bf2f(vr.x);
        ay = ay * c + p * bf2f(vr.y);
        m = mn;

        s0 = s1; f0 = f1; s1 = s2; f1 = f2;
    }
    const float inv = (end > beg) ? 1.f / z : 0.f;
    float2 o; o.x = ax * inv; o.y = ay * inv;
    *(float2*)(agg + (size_t)wid * NDIM + 2 * lane) = o;
}

extern "C" void kernel_launch(void* const* d_in, const int* in_sizes, int n_in,
                              void* d_out, int out_size, void* d_ws, size_t ws_size,
                              hipStream_t stream)
{
    const float* feat0 = (const float*)d_in[0];
    const float* feat1 = (const float*)d_in[1];
    const float* ev0 = (const float*)d_in[2];
    const float* ev1 = (const float*)d_in[3];
    const float* ev2 = (const float*)d_in[4];
    const int* src0 = (const int*)d_in[5];
    const int* dst0 = (const int*)d_in[6];
    const int* src1 = (const int*)d_in[7];
    const int* dst1 = (const int*)d_in[8];
    const int* src2 = (const int*)d_in[9];
    const int* dst2 = (const int*)d_in[10];
    const float* Kw = (const float*)d_in[11];
    const float* Kb = (const float*)d_in[12];
    const float* Qw = (const float*)d_in[13];
    const float* Qb = (const float*)d_in[14];
    const float* Vw = (const float*)d_in[15];
    const float* Vb = (const float*)d_in[16];
    const float* Aw = (const float*)d_in[17];
    const float* Ab = (const float*)d_in[18];
    const float* ew = (const float*)d_in[19];
    const float* eb = (const float*)d_in[20];
    const float* skip = (const float*)d_in[21];

    const int n0 = in_sizes[0] / NDIM;
    const int n1 = in_sizes[1] / NDIM;
    const int E0 = in_sizes[5];
    const int E1 = in_sizes[7];
    const int E2 = in_sizes[9];

    auto rup = [](size_t b) { return (b + 255) & ~size_t(255); };
    const size_t need =
        rup((size_t)n0 * NDIM * 2) * 3 +          // K0 Q0 V0 (bf16)
        rup((size_t)n1 * NDIM * 2) * 3 +          // K1 Q1 V1 (bf16)
        rup((size_t)n1 * NDIM * 4) +              // agg1
        rup((size_t)n0 * NDIM * 4) * 2 +          // agg0a agg0b
        rup((size_t)(n1 + 1) * 4) +
        rup((size_t)(n0 + 1) * 4) * 2 +
        rup((size_t)(n1 + n0 + n0) * 4) +
        rup((size_t)3 * MAXNB * 4) +              // scan partials
        (rup((size_t)E0 * 4) + rup((size_t)E1 * 4) + rup((size_t)E2 * 4)) * 2;
    if (ws_size < need) return;

    char* p = (char*)d_ws;
    auto alloc = [&](size_t bytes) -> char* {
        char* r = p;
        p += (bytes + 255) & ~size_t(255);
        return r;
    };
    unsigned short* K0 = (unsigned short*)alloc((size_t)n0 * NDIM * 2);
    unsigned short* Q0 = (unsigned short*)alloc((size_t)n0 * NDIM * 2);
    unsigned short* V0 = (unsigned short*)alloc((size_t)n0 * NDIM * 2);
    unsigned short* K1 = (unsigned short*)alloc((size_t)n1 * NDIM * 2);
    unsigned short* Q1 = (unsigned short*)alloc((size_t)n1 * NDIM * 2);
    unsigned short* V1 = (unsigned short*)alloc((size_t)n1 * NDIM * 2);
    float* agg1  = (float*)alloc((size_t)n1 * NDIM * 4);
    float* agg0a = (float*)alloc((size_t)n0 * NDIM * 4);
    float* agg0b = (float*)alloc((size_t)n0 * NDIM * 4);
    int* off0 = (int*)alloc((size_t)(n1 + 1) * 4);
    int* off1 = (int*)alloc((size_t)(n0 + 1) * 4);
    int* off2 = (int*)alloc((size_t)(n0 + 1) * 4);
    int* posA = (int*)alloc((size_t)(n1 + n0 + n0) * 4);
    int* pos0 = posA;
    int* pos1 = posA + n1;
    int* pos2 = posA + n1 + n0;
    int* partial = (int*)alloc((size_t)3 * MAXNB * 4);
    int*   srcs0 = (int*)alloc((size_t)E0 * 4);
    float* evs0  = (float*)alloc((size_t)E0 * 4);
    int*   srcs1 = (int*)alloc((size_t)E1 * 4);
    float* evs1  = (float*)alloc((size_t)E1 * 4);
    int*   srcs2 = (int*)alloc((size_t)E2 * 4);
    float* evs2  = (float*)alloc((size_t)E2 * 4);

    const int W2 = NDIM * NDIM;
    dim3 blk(256);
    dim3 g0((n0 + 63) / 64), g1((n1 + 63) / 64);
    gemm_node<<<g0, blk, 0, stream>>>(feat0, Kw,       Kb,        K0, n0);
    gemm_node<<<g0, blk, 0, stream>>>(feat0, Qw,       Qb,        Q0, n0);
    gemm_node<<<g0, blk, 0, stream>>>(feat0, Vw,       Vb,        V0, n0);
    gemm_node<<<g1, blk, 0, stream>>>(feat1, Kw + W2,  Kb + NDIM, K1, n1);
    gemm_node<<<g1, blk, 0, stream>>>(feat1, Qw + W2,  Qb + NDIM, Q1, n1);
    gemm_node<<<g1, blk, 0, stream>>>(feat1, Vw + W2,  Vb + NDIM, V1, n1);

    hipMemsetAsync(posA, 0, (size_t)(n1 + n0 + n0) * 4, stream);
    hist_kernel<<<2048, 256, 0, stream>>>(dst0, E0, pos0);
    hist_kernel<<<2048, 256, 0, stream>>>(dst1, E1, pos1);
    hist_kernel<<<2048, 256, 0, stream>>>(dst2, E2, pos2);

    const int nmax = (n0 > n1) ? n0 : n1;
    const int nb = (nmax + SCH - 1) / SCH;          // <= MAXNB
    scan_partial<<<dim3(nb, 3), blk, 0, stream>>>(pos0, n1, pos1, n0, pos2, n0, partial);
    scan_base<<<1, 64, 0, stream>>>(partial, n1, n0, n0, off0, off1, off2);
    scan_final<<<dim3(nb, 3), blk, 0, stream>>>(pos0, n1, off0, pos1, n0, off1, pos2, n0, off2, partial);

    scatter_kernel<<<2048, 256, 0, stream>>>(dst0, src0, ev0, E0, pos0, srcs0, evs0);
    scatter_kernel<<<2048, 256, 0, stream>>>(dst1, src1, ev1, E1, pos1, srcs1, evs1);
    scatter_kernel<<<2048, 256, 0, stream>>>(dst2, src2, ev2, E2, pos2, srcs2, evs2);

    edge_agg<<<(n1 + 3) / 4, blk, 0, stream>>>(off0, srcs0, evs0, K0, Q1, V0, ew, eb, agg1, n1);
    edge_agg<<<(n0 + 3) / 4, blk, 0, stream>>>(off1, srcs1, evs1, K1, Q0, V1, ew, eb, agg0a, n0);
    edge_agg<<<(n0 + 3) / 4, blk, 0, stream>>>(off2, srcs2, evs2, K0, Q0, V0, ew, eb, agg0b, n0);

    float* out = (float*)d_out;
    gemm_out<true ><<<g0, blk, 0, stream>>>(agg0a, agg0b, Aw,      Ab,        feat0, skip, 0, out, n0);
    gemm_out<false><<<g1, blk, 0, stream>>>(agg1,  nullptr, Aw + W2, Ab + NDIM, feat1, skip, 1, out + (size_t)n0 * NDIM, n1);
}

// Round 7
// 699.444 us; speedup vs baseline: 1.9177x; 1.1193x over previous
//
#include <hip/hip_runtime.h>
#include <hip/hip_bf16.h>
#include <math.h>

// HEAT layer. Round 7: (a) edge_agg2 — 2 dsts/wave, 4 dims/lane, log2-domain
// defer-max online softmax; (b) MFMA bf16 GEMMs (fused KQV + output transform).

#define NDIM 128
#define SCH 2048
#define MAXNB 64

typedef __attribute__((ext_vector_type(8))) short short8;
typedef __attribute__((ext_vector_type(4))) float f32x4;

__device__ __forceinline__ float bf2f(unsigned short u) {
    union { unsigned int i; float f; } x; x.i = ((unsigned int)u) << 16; return x.f;
}
__device__ __forceinline__ unsigned short f2bf(float f) {
    unsigned int u = __float_as_uint(f);
    unsigned int r = (u + 0x7FFFu + ((u >> 16) & 1u)) >> 16;   // RNE
    return (unsigned short)r;
}

// ---------------- weight prep: 8 mats (t0:K,Q,V,A; t1:K,Q,V,A) f32[k][n] -> bf16 [n][k] ----------------
__global__ void wt_prep(const float* __restrict__ Kw, const float* __restrict__ Qw,
                        const float* __restrict__ Vw, const float* __restrict__ Aw,
                        unsigned short* __restrict__ Wtbuf)
{
    const int b = blockIdx.x;        // t*4 + m
    const int t = b >> 2, m = b & 3;
    const float* src = (m == 0 ? Kw : m == 1 ? Qw : m == 2 ? Vw : Aw) + (size_t)t * 16384;
    unsigned short* dst = Wtbuf + (size_t)b * 16384;
    for (int i = threadIdx.x; i < 16384; i += blockDim.x) {
        const int k = i >> 7, nn = i & 127;
        dst[nn * 128 + k] = f2bf(src[i]);
    }
}

// ---------------- fused K/Q/V MFMA GEMM: out(bf16) = feat(f32->bf16) @ W + b ----------------
__global__ __launch_bounds__(256) void gemm_kqv(const float* __restrict__ feat,
                                                const unsigned short* __restrict__ Wt,  // 3 mats [n][k] bf16
                                                const float* __restrict__ Kb, const float* __restrict__ Qb,
                                                const float* __restrict__ Vb,
                                                unsigned short* __restrict__ Ko, unsigned short* __restrict__ Qo,
                                                unsigned short* __restrict__ Vo, int n)
{
    const int tid = threadIdx.x;
    const int w = tid >> 6, lane = tid & 63;
    const int r16 = lane & 15, kg = lane >> 4;
    const int wrow = blockIdx.x * 64 + w * 16;
    const int arow = min(wrow + r16, n - 1);

    short8 afr[4];
#pragma unroll
    for (int k0i = 0; k0i < 4; ++k0i) {
        const float* ap = feat + (size_t)arow * NDIM + k0i * 32 + kg * 8;
        const float4 lo = *(const float4*)ap;
        const float4 hi = *(const float4*)(ap + 4);
        short8 a;
        a[0] = (short)f2bf(lo.x); a[1] = (short)f2bf(lo.y);
        a[2] = (short)f2bf(lo.z); a[3] = (short)f2bf(lo.w);
        a[4] = (short)f2bf(hi.x); a[5] = (short)f2bf(hi.y);
        a[6] = (short)f2bf(hi.z); a[7] = (short)f2bf(hi.w);
        afr[k0i] = a;
    }

    const float* biases[3] = {Kb, Qb, Vb};
    unsigned short* outs[3] = {Ko, Qo, Vo};
#pragma unroll
    for (int m = 0; m < 3; ++m) {
        const unsigned short* wt = Wt + (size_t)m * 16384;
        f32x4 acc[8];
#pragma unroll
        for (int c = 0; c < 8; ++c) acc[c] = (f32x4){0.f, 0.f, 0.f, 0.f};
#pragma unroll
        for (int k0i = 0; k0i < 4; ++k0i)
#pragma unroll
            for (int c = 0; c < 8; ++c) {
                const short8 b = *(const short8*)(wt + (size_t)(16 * c + r16) * NDIM + k0i * 32 + kg * 8);
                acc[c] = __builtin_amdgcn_mfma_f32_16x16x32_bf16(afr[k0i], b, acc[c], 0, 0, 0);
            }
#pragma unroll
        for (int c = 0; c < 8; ++c) {
            const int col = 16 * c + r16;
            const float bb = biases[m][col];
#pragma unroll
            for (int j = 0; j < 4; ++j) {
                const int row = wrow + kg * 4 + j;
                if (row < n) outs[m][(size_t)row * NDIM + col] = f2bf(acc[c][j] + bb);
            }
        }
    }
}

// ---------------- output MFMA GEMM: C = (agg @ Aw + Ab)*alpha + feat*(1-alpha) ----------------
template <bool AVG>
__global__ __launch_bounds__(256) void gemm_out2(const unsigned short* __restrict__ A1,
                                                 const unsigned short* __restrict__ A2,
                                                 const unsigned short* __restrict__ Wt,
                                                 const float* __restrict__ bias,
                                                 const float* __restrict__ feat,
                                                 const float* __restrict__ skip, int nid,
                                                 float* __restrict__ C, int n)
{
    const int tid = threadIdx.x;
    const int w = tid >> 6, lane = tid & 63;
    const int r16 = lane & 15, kg = lane >> 4;
    const int wrow = blockIdx.x * 64 + w * 16;
    const int arow = min(wrow + r16, n - 1);

    short8 afr[4];
#pragma unroll
    for (int k0i = 0; k0i < 4; ++k0i) {
        short8 a = *(const short8*)(A1 + (size_t)arow * NDIM + k0i * 32 + kg * 8);
        if (AVG) {
            const short8 b = *(const short8*)(A2 + (size_t)arow * NDIM + k0i * 32 + kg * 8);
#pragma unroll
            for (int j = 0; j < 8; ++j) {
                const float v = 0.5f * (bf2f((unsigned short)a[j]) + bf2f((unsigned short)b[j]));
                a[j] = (short)f2bf(v);
            }
        }
        afr[k0i] = a;
    }
    f32x4 acc[8];
#pragma unroll
    for (int c = 0; c < 8; ++c) acc[c] = (f32x4){0.f, 0.f, 0.f, 0.f};
#pragma unroll
    for (int k0i = 0; k0i < 4; ++k0i)
#pragma unroll
        for (int c = 0; c < 8; ++c) {
            const short8 b = *(const short8*)(Wt + (size_t)(16 * c + r16) * NDIM + k0i * 32 + kg * 8);
            acc[c] = __builtin_amdgcn_mfma_f32_16x16x32_bf16(afr[k0i], b, acc[c], 0, 0, 0);
        }
    const float sk = skip[nid];
    const float alpha = 1.f / (1.f + __expf(-sk));
    const float beta = 1.f - alpha;
#pragma unroll
    for (int c = 0; c < 8; ++c) {
        const int col = 16 * c + r16;
        const float bb = bias[col];
#pragma unroll
        for (int j = 0; j < 4; ++j) {
            const int row = wrow + kg * 4 + j;
            if (row < n)
                C[(size_t)row * NDIM + col] = (acc[c][j] + bb) * alpha + feat[(size_t)row * NDIM + col] * beta;
        }
    }
}

// ---------------- CSR build ----------------
__global__ void hist_kernel(const int* __restrict__ dst, int E, int* __restrict__ cnt)
{
    for (int i = blockIdx.x * blockDim.x + threadIdx.x; i < E; i += gridDim.x * blockDim.x)
        atomicAdd(&cnt[dst[i]], 1);
}

__global__ __launch_bounds__(256) void scan_partial(
    const int* __restrict__ c0, int nA, const int* __restrict__ c1, int nB,
    const int* __restrict__ c2, int nC, int* __restrict__ partial)
{
    const int seg = blockIdx.y;
    const int* c = seg == 0 ? c0 : (seg == 1 ? c1 : c2);
    const int n = seg == 0 ? nA : (seg == 1 ? nB : nC);
    const int beg = blockIdx.x * SCH;
    const int t = threadIdx.x;
    int s = 0;
    if (beg < n) {
        const int base_i = beg + t * 8;
#pragma unroll
        for (int j = 0; j < 8; ++j) {
            const int i = base_i + j;
            if (i < n) s += c[i];
        }
    }
#pragma unroll
    for (int o = 1; o < 64; o <<= 1) s += __shfl_xor(s, o);
    __shared__ int ws[4];
    const int lane = t & 63, w = t >> 6;
    if (lane == 0) ws[w] = s;
    __syncthreads();
    if (t == 0) partial[seg * MAXNB + blockIdx.x] = ws[0] + ws[1] + ws[2] + ws[3];
}

__global__ void scan_base(int* __restrict__ partial, int nA, int nB, int nC,
                          int* __restrict__ offA, int* __restrict__ offB, int* __restrict__ offC)
{
    const int seg = threadIdx.x;
    if (seg >= 3) return;
    const int n = seg == 0 ? nA : (seg == 1 ? nB : nC);
    int* off = seg == 0 ? offA : (seg == 1 ? offB : offC);
    const int nb = (n + SCH - 1) / SCH;
    int run = 0;
    for (int b = 0; b < nb; ++b) {
        const int v = partial[seg * MAXNB + b];
        partial[seg * MAXNB + b] = run;
        run += v;
    }
    off[n] = run;
}

__global__ __launch_bounds__(256) void scan_final(
    int* __restrict__ c0, int nA, int* __restrict__ offA,
    int* __restrict__ c1, int nB, int* __restrict__ offB,
    int* __restrict__ c2, int nC, int* __restrict__ offC,
    const int* __restrict__ partial)
{
    const int seg = blockIdx.y;
    int* c = seg == 0 ? c0 : (seg == 1 ? c1 : c2);
    int* off = seg == 0 ? offA : (seg == 1 ? offB : offC);
    const int n = seg == 0 ? nA : (seg == 1 ? nB : nC);
    const int beg = blockIdx.x * SCH;
    if (beg >= n) return;
    const int t = threadIdx.x, lane = t & 63, w = t >> 6;
    const int base_i = beg + t * 8;

    int v[8];
    int run = 0;
#pragma unroll
    for (int j = 0; j < 8; ++j) {
        const int i = base_i + j;
        const int x = (i < n) ? c[i] : 0;
        v[j] = run;
        run += x;
    }
    const int tsum = run;
    int x = tsum;
#pragma unroll
    for (int o = 1; o < 64; o <<= 1) {
        const int y = __shfl_up(x, o);
        if (lane >= o) x += y;
    }
    const int wexc = x - tsum;
    __shared__ int wsum[4];
    if (lane == 63) wsum[w] = x;
    __syncthreads();
    int wbase = 0;
    for (int i = 0; i < w; ++i) wbase += wsum[i];
    const int base = partial[seg * MAXNB + blockIdx.x] + wbase + wexc;
#pragma unroll
    for (int j = 0; j < 8; ++j) {
        const int i = base_i + j;
        if (i < n) {
            const int e = base + v[j];
            off[i] = e;
            c[i] = e;
        }
    }
}

__global__ void scatter_kernel(const int* __restrict__ dst, const int* __restrict__ src,
                               const float* __restrict__ ev, int E,
                               int* __restrict__ pos,
                               int* __restrict__ srcs_p, float* __restrict__ evs_p)
{
    for (int i = blockIdx.x * blockDim.x + threadIdx.x; i < E; i += gridDim.x * blockDim.x) {
        const int d = dst[i];
        const int p = atomicAdd(&pos[d], 1);
        srcs_p[p] = src[i];
        evs_p[p] = ev[i];
    }
}

// ---------------- edge aggregation v2: 2 dsts per wave, 4 dims/lane, defer-max ----------------
__global__ __launch_bounds__(256) void edge_agg2(const int* __restrict__ off,
                                                 const int* __restrict__ srcs,
                                                 const float* __restrict__ evs,
                                                 const unsigned short* __restrict__ K,
                                                 const unsigned short* __restrict__ Q,
                                                 const unsigned short* __restrict__ V,
                                                 const float* __restrict__ ew,
                                                 const float* __restrict__ eb,
                                                 unsigned short* __restrict__ aggb, int n_dst)
{
    const int wv = (blockIdx.x * blockDim.x + threadIdx.x) >> 6;
    const int lane = threadIdx.x & 63;
    const int half = lane >> 5, l5 = lane & 31;
    const int dst = 2 * wv + half;
    const bool valid = dst < n_dst;
    int beg = 0, end = 0;
    if (valid) { beg = off[dst]; end = off[dst + 1]; }
    const int len = end - beg;
    const int maxLen = max(len, __shfl_xor(len, 32));
    if (maxLen == 0) {
        if (valid) *(ushort4*)(aggb + (size_t)dst * NDIM + 4 * l5) = (ushort4){0, 0, 0, 0};
        return;
    }
    const float LOG2E = 1.4426950408889634f;
    const float ews = ew[0] * 0.25f * LOG2E;   // fold /sqrt(16) and ln2
    const float ebs = eb[0] * 0.25f * LOG2E;
    float qx = 0.f, qy = 0.f, qz = 0.f, qw = 0.f;
    if (valid) {
        const ushort4 qr = *(const ushort4*)(Q + (size_t)dst * NDIM + 4 * l5);
        qx = bf2f(qr.x); qy = bf2f(qr.y); qz = bf2f(qr.z); qw = bf2f(qr.w);
    }
    float m2 = -3e38f, z = 0.f;
    float a0 = 0.f, a1 = 0.f, a2 = 0.f, a3 = 0.f;

    int s0 = 0, s1 = 0;
    float f0 = 0.f, f1 = 0.f;
    if (0 < len) { s0 = srcs[beg]; f0 = evs[beg]; }
    if (1 < len) { s1 = srcs[beg + 1]; f1 = evs[beg + 1]; }

    for (int t = 0; t < maxLen; ++t) {
        const bool act = t < len;
        const ushort4 kr = *(const ushort4*)(K + (size_t)s0 * NDIM + 4 * l5);
        const ushort4 vr = *(const ushort4*)(V + (size_t)s0 * NDIM + 4 * l5);
        int sNext = 0; float fNext = 0.f;
        if (t + 2 < len) { sNext = srcs[beg + t + 2]; fNext = evs[beg + t + 2]; }
        const float f = f0 * ews + ebs;

        float d = qx * bf2f(kr.x) + qy * bf2f(kr.y) + qz * bf2f(kr.z) + qw * bf2f(kr.w);
        d += __shfl_xor(d, 1);
        d += __shfl_xor(d, 2);
        const float sc2 = d * f;             // log2-domain score
        if (__any(act && (sc2 > m2 + 8.f))) {
            const float mn = act ? fmaxf(m2, sc2) : m2;
            const float c = exp2f(m2 - mn);
            z *= c; a0 *= c; a1 *= c; a2 *= c; a3 *= c;
            m2 = mn;
        }
        const float p = act ? exp2f(sc2 - m2) : 0.f;
        z += p;
        a0 += p * bf2f(vr.x);
        a1 += p * bf2f(vr.y);
        a2 += p * bf2f(vr.z);
        a3 += p * bf2f(vr.w);

        s0 = s1; f0 = f1; s1 = sNext; f1 = fNext;
    }
    if (valid) {
        const float inv = (len > 0) ? 1.f / z : 0.f;
        ushort4 o;
        o.x = f2bf(a0 * inv); o.y = f2bf(a1 * inv);
        o.z = f2bf(a2 * inv); o.w = f2bf(a3 * inv);
        *(ushort4*)(aggb + (size_t)dst * NDIM + 4 * l5) = o;
    }
}

extern "C" void kernel_launch(void* const* d_in, const int* in_sizes, int n_in,
                              void* d_out, int out_size, void* d_ws, size_t ws_size,
                              hipStream_t stream)
{
    const float* feat0 = (const float*)d_in[0];
    const float* feat1 = (const float*)d_in[1];
    const float* ev0 = (const float*)d_in[2];
    const float* ev1 = (const float*)d_in[3];
    const float* ev2 = (const float*)d_in[4];
    const int* src0 = (const int*)d_in[5];
    const int* dst0 = (const int*)d_in[6];
    const int* src1 = (const int*)d_in[7];
    const int* dst1 = (const int*)d_in[8];
    const int* src2 = (const int*)d_in[9];
    const int* dst2 = (const int*)d_in[10];
    const float* Kw = (const float*)d_in[11];
    const float* Kb = (const float*)d_in[12];
    const float* Qw = (const float*)d_in[13];
    const float* Qb = (const float*)d_in[14];
    const float* Vw = (const float*)d_in[15];
    const float* Vb = (const float*)d_in[16];
    const float* Aw = (const float*)d_in[17];
    const float* Ab = (const float*)d_in[18];
    const float* ew = (const float*)d_in[19];
    const float* eb = (const float*)d_in[20];
    const float* skip = (const float*)d_in[21];

    const int n0 = in_sizes[0] / NDIM;
    const int n1 = in_sizes[1] / NDIM;
    const int E0 = in_sizes[5];
    const int E1 = in_sizes[7];
    const int E2 = in_sizes[9];

    auto rup = [](size_t b) { return (b + 255) & ~size_t(255); };
    const size_t need =
        rup((size_t)8 * 16384 * 2) +                 // Wt buf (8 mats bf16)
        rup((size_t)n0 * NDIM * 2) * 3 +             // K0 Q0 V0 bf16
        rup((size_t)n1 * NDIM * 2) * 3 +             // K1 Q1 V1 bf16
        rup((size_t)n1 * NDIM * 2) +                 // aggb1
        rup((size_t)n0 * NDIM * 2) * 2 +             // aggb0a aggb0b
        rup((size_t)(n1 + 1) * 4) +
        rup((size_t)(n0 + 1) * 4) * 2 +
        rup((size_t)(n1 + n0 + n0) * 4) +
        rup((size_t)3 * MAXNB * 4) +
        (rup((size_t)E0 * 4) + rup((size_t)E1 * 4) + rup((size_t)E2 * 4)) * 2;
    if (ws_size < need) return;

    char* p = (char*)d_ws;
    auto alloc = [&](size_t bytes) -> char* {
        char* r = p;
        p += (bytes + 255) & ~size_t(255);
        return r;
    };
    unsigned short* Wtbuf = (unsigned short*)alloc((size_t)8 * 16384 * 2);
    unsigned short* K0 = (unsigned short*)alloc((size_t)n0 * NDIM * 2);
    unsigned short* Q0 = (unsigned short*)alloc((size_t)n0 * NDIM * 2);
    unsigned short* V0 = (unsigned short*)alloc((size_t)n0 * NDIM * 2);
    unsigned short* K1 = (unsigned short*)alloc((size_t)n1 * NDIM * 2);
    unsigned short* Q1 = (unsigned short*)alloc((size_t)n1 * NDIM * 2);
    unsigned short* V1 = (unsigned short*)alloc((size_t)n1 * NDIM * 2);
    unsigned short* aggb1  = (unsigned short*)alloc((size_t)n1 * NDIM * 2);
    unsigned short* aggb0a = (unsigned short*)alloc((size_t)n0 * NDIM * 2);
    unsigned short* aggb0b = (unsigned short*)alloc((size_t)n0 * NDIM * 2);
    int* off0 = (int*)alloc((size_t)(n1 + 1) * 4);
    int* off1 = (int*)alloc((size_t)(n0 + 1) * 4);
    int* off2 = (int*)alloc((size_t)(n0 + 1) * 4);
    int* posA = (int*)alloc((size_t)(n1 + n0 + n0) * 4);
    int* pos0 = posA;
    int* pos1 = posA + n1;
    int* pos2 = posA + n1 + n0;
    int* partial = (int*)alloc((size_t)3 * MAXNB * 4);
    int*   srcs0 = (int*)alloc((size_t)E0 * 4);
    float* evs0  = (float*)alloc((size_t)E0 * 4);
    int*   srcs1 = (int*)alloc((size_t)E1 * 4);
    float* evs1  = (float*)alloc((size_t)E1 * 4);
    int*   srcs2 = (int*)alloc((size_t)E2 * 4);
    float* evs2  = (float*)alloc((size_t)E2 * 4);

    dim3 blk(256);
    dim3 g0((n0 + 63) / 64), g1((n1 + 63) / 64);

    // weights -> bf16 transposed
    wt_prep<<<8, 256, 0, stream>>>(Kw, Qw, Vw, Aw, Wtbuf);

    // fused K/Q/V MFMA GEMMs (per node type)
    gemm_kqv<<<g0, blk, 0, stream>>>(feat0, Wtbuf,             Kb,        Qb,        Vb,        K0, Q0, V0, n0);
    gemm_kqv<<<g1, blk, 0, stream>>>(feat1, Wtbuf + 4 * 16384, Kb + NDIM, Qb + NDIM, Vb + NDIM, K1, Q1, V1, n1);

    // CSR build
    hipMemsetAsync(posA, 0, (size_t)(n1 + n0 + n0) * 4, stream);
    hist_kernel<<<2048, 256, 0, stream>>>(dst0, E0, pos0);
    hist_kernel<<<2048, 256, 0, stream>>>(dst1, E1, pos1);
    hist_kernel<<<2048, 256, 0, stream>>>(dst2, E2, pos2);

    const int nmax = (n0 > n1) ? n0 : n1;
    const int nb = (nmax + SCH - 1) / SCH;
    scan_partial<<<dim3(nb, 3), blk, 0, stream>>>(pos0, n1, pos1, n0, pos2, n0, partial);
    scan_base<<<1, 64, 0, stream>>>(partial, n1, n0, n0, off0, off1, off2);
    scan_final<<<dim3(nb, 3), blk, 0, stream>>>(pos0, n1, off0, pos1, n0, off1, pos2, n0, off2, partial);

    scatter_kernel<<<2048, 256, 0, stream>>>(dst0, src0, ev0, E0, pos0, srcs0, evs0);
    scatter_kernel<<<2048, 256, 0, stream>>>(dst1, src1, ev1, E1, pos1, srcs1, evs1);
    scatter_kernel<<<2048, 256, 0, stream>>>(dst2, src2, ev2, E2, pos2, srcs2, evs2);

    // edge aggregation (2 dsts per wave)
    const int eb1 = ((n1 + 1) / 2 + 3) / 4;
    const int eb0 = ((n0 + 1) / 2 + 3) / 4;
    edge_agg2<<<eb1, blk, 0, stream>>>(off0, srcs0, evs0, K0, Q1, V0, ew, eb, aggb1, n1);
    edge_agg2<<<eb0, blk, 0, stream>>>(off1, srcs1, evs1, K1, Q0, V1, ew, eb, aggb0a, n0);
    edge_agg2<<<eb0, blk, 0, stream>>>(off2, srcs2, evs2, K0, Q0, V0, ew, eb, aggb0b, n0);

    // output transform (MFMA)
    float* out = (float*)d_out;
    gemm_out2<true ><<<g0, blk, 0, stream>>>(aggb0a, aggb0b, Wtbuf + 3 * 16384, Ab,        feat0, skip, 0, out, n0);
    gemm_out2<false><<<g1, blk, 0, stream>>>(aggb1,  nullptr, Wtbuf + 7 * 16384, Ab + NDIM, feat1, skip, 1, out + (size_t)n0 * NDIM, n1);
}

// Round 9
// 687.707 us; speedup vs baseline: 1.9504x; 1.0171x over previous
//
#include <hip/hip_runtime.h>
#include <hip/hip_bf16.h>
#include <math.h>

// HEAT layer. Round 8 (resubmit): fused CSR build (hist3/scatter3, int2 edge payload),
// fused 3-etype edge_agg with no-max exp2 softmax + chunked shfl-broadcast
// index prefetch. MFMA GEMMs unchanged from round 7.

#define NDIM 128
#define SCH 2048
#define MAXNB 64

typedef __attribute__((ext_vector_type(8))) short short8;
typedef __attribute__((ext_vector_type(4))) float f32x4;

__device__ __forceinline__ float bf2f(unsigned short u) {
    union { unsigned int i; float f; } x; x.i = ((unsigned int)u) << 16; return x.f;
}
__device__ __forceinline__ unsigned short f2bf(float f) {
    unsigned int u = __float_as_uint(f);
    unsigned int r = (u + 0x7FFFu + ((u >> 16) & 1u)) >> 16;   // RNE
    return (unsigned short)r;
}

// ---------------- weight prep: 8 mats f32[k][n] -> bf16 [n][k] ----------------
__global__ void wt_prep(const float* __restrict__ Kw, const float* __restrict__ Qw,
                        const float* __restrict__ Vw, const float* __restrict__ Aw,
                        unsigned short* __restrict__ Wtbuf)
{
    const int b = blockIdx.x;        // t*4 + m
    const int t = b >> 2, m = b & 3;
    const float* src = (m == 0 ? Kw : m == 1 ? Qw : m == 2 ? Vw : Aw) + (size_t)t * 16384;
    unsigned short* dst = Wtbuf + (size_t)b * 16384;
    for (int i = threadIdx.x; i < 16384; i += blockDim.x) {
        const int k = i >> 7, nn = i & 127;
        dst[nn * 128 + k] = f2bf(src[i]);
    }
}

// ---------------- fused K/Q/V MFMA GEMM ----------------
__global__ __launch_bounds__(256) void gemm_kqv(const float* __restrict__ feat,
                                                const unsigned short* __restrict__ Wt,
                                                const float* __restrict__ Kb, const float* __restrict__ Qb,
                                                const float* __restrict__ Vb,
                                                unsigned short* __restrict__ Ko, unsigned short* __restrict__ Qo,
                                                unsigned short* __restrict__ Vo, int n)
{
    const int tid = threadIdx.x;
    const int w = tid >> 6, lane = tid & 63;
    const int r16 = lane & 15, kg = lane >> 4;
    const int wrow = blockIdx.x * 64 + w * 16;
    const int arow = min(wrow + r16, n - 1);

    short8 afr[4];
#pragma unroll
    for (int k0i = 0; k0i < 4; ++k0i) {
        const float* ap = feat + (size_t)arow * NDIM + k0i * 32 + kg * 8;
        const float4 lo = *(const float4*)ap;
        const float4 hi = *(const float4*)(ap + 4);
        short8 a;
        a[0] = (short)f2bf(lo.x); a[1] = (short)f2bf(lo.y);
        a[2] = (short)f2bf(lo.z); a[3] = (short)f2bf(lo.w);
        a[4] = (short)f2bf(hi.x); a[5] = (short)f2bf(hi.y);
        a[6] = (short)f2bf(hi.z); a[7] = (short)f2bf(hi.w);
        afr[k0i] = a;
    }

    const float* biases[3] = {Kb, Qb, Vb};
    unsigned short* outs[3] = {Ko, Qo, Vo};
#pragma unroll
    for (int m = 0; m < 3; ++m) {
        const unsigned short* wt = Wt + (size_t)m * 16384;
        f32x4 acc[8];
#pragma unroll
        for (int c = 0; c < 8; ++c) acc[c] = (f32x4){0.f, 0.f, 0.f, 0.f};
#pragma unroll
        for (int k0i = 0; k0i < 4; ++k0i)
#pragma unroll
            for (int c = 0; c < 8; ++c) {
                const short8 b = *(const short8*)(wt + (size_t)(16 * c + r16) * NDIM + k0i * 32 + kg * 8);
                acc[c] = __builtin_amdgcn_mfma_f32_16x16x32_bf16(afr[k0i], b, acc[c], 0, 0, 0);
            }
#pragma unroll
        for (int c = 0; c < 8; ++c) {
            const int col = 16 * c + r16;
            const float bb = biases[m][col];
#pragma unroll
            for (int j = 0; j < 4; ++j) {
                const int row = wrow + kg * 4 + j;
                if (row < n) outs[m][(size_t)row * NDIM + col] = f2bf(acc[c][j] + bb);
            }
        }
    }
}

// ---------------- output MFMA GEMM ----------------
template <bool AVG>
__global__ __launch_bounds__(256) void gemm_out2(const unsigned short* __restrict__ A1,
                                                 const unsigned short* __restrict__ A2,
                                                 const unsigned short* __restrict__ Wt,
                                                 const float* __restrict__ bias,
                                                 const float* __restrict__ feat,
                                                 const float* __restrict__ skip, int nid,
                                                 float* __restrict__ C, int n)
{
    const int tid = threadIdx.x;
    const int w = tid >> 6, lane = tid & 63;
    const int r16 = lane & 15, kg = lane >> 4;
    const int wrow = blockIdx.x * 64 + w * 16;
    const int arow = min(wrow + r16, n - 1);

    short8 afr[4];
#pragma unroll
    for (int k0i = 0; k0i < 4; ++k0i) {
        short8 a = *(const short8*)(A1 + (size_t)arow * NDIM + k0i * 32 + kg * 8);
        if (AVG) {
            const short8 b = *(const short8*)(A2 + (size_t)arow * NDIM + k0i * 32 + kg * 8);
#pragma unroll
            for (int j = 0; j < 8; ++j) {
                const float v = 0.5f * (bf2f((unsigned short)a[j]) + bf2f((unsigned short)b[j]));
                a[j] = (short)f2bf(v);
            }
        }
        afr[k0i] = a;
    }
    f32x4 acc[8];
#pragma unroll
    for (int c = 0; c < 8; ++c) acc[c] = (f32x4){0.f, 0.f, 0.f, 0.f};
#pragma unroll
    for (int k0i = 0; k0i < 4; ++k0i)
#pragma unroll
        for (int c = 0; c < 8; ++c) {
            const short8 b = *(const short8*)(Wt + (size_t)(16 * c + r16) * NDIM + k0i * 32 + kg * 8);
            acc[c] = __builtin_amdgcn_mfma_f32_16x16x32_bf16(afr[k0i], b, acc[c], 0, 0, 0);
        }
    const float sk = skip[nid];
    const float alpha = 1.f / (1.f + __expf(-sk));
    const float beta = 1.f - alpha;
#pragma unroll
    for (int c = 0; c < 8; ++c) {
        const int col = 16 * c + r16;
        const float bb = bias[col];
#pragma unroll
        for (int j = 0; j < 4; ++j) {
            const int row = wrow + kg * 4 + j;
            if (row < n)
                C[(size_t)row * NDIM + col] = (acc[c][j] + bb) * alpha + feat[(size_t)row * NDIM + col] * beta;
        }
    }
}

// ---------------- CSR build (fused over 3 etypes) ----------------
__global__ void hist3(const int* __restrict__ d0, int E0, int* __restrict__ p0,
                      const int* __restrict__ d1, int E1, int* __restrict__ p1,
                      const int* __restrict__ d2, int E2, int* __restrict__ p2)
{
    const int seg = blockIdx.y;
    const int* dst = seg == 0 ? d0 : (seg == 1 ? d1 : d2);
    int* cnt = seg == 0 ? p0 : (seg == 1 ? p1 : p2);
    const int E = seg == 0 ? E0 : (seg == 1 ? E1 : E2);
    for (int i = blockIdx.x * blockDim.x + threadIdx.x; i < E; i += gridDim.x * blockDim.x)
        atomicAdd(&cnt[dst[i]], 1);
}

__global__ __launch_bounds__(256) void scan_partial(
    const int* __restrict__ c0, int nA, const int* __restrict__ c1, int nB,
    const int* __restrict__ c2, int nC, int* __restrict__ partial)
{
    const int seg = blockIdx.y;
    const int* c = seg == 0 ? c0 : (seg == 1 ? c1 : c2);
    const int n = seg == 0 ? nA : (seg == 1 ? nB : nC);
    const int beg = blockIdx.x * SCH;
    const int t = threadIdx.x;
    int s = 0;
    if (beg < n) {
        const int base_i = beg + t * 8;
#pragma unroll
        for (int j = 0; j < 8; ++j) {
            const int i = base_i + j;
            if (i < n) s += c[i];
        }
    }
#pragma unroll
    for (int o = 1; o < 64; o <<= 1) s += __shfl_xor(s, o);
    __shared__ int ws[4];
    const int lane = t & 63, w = t >> 6;
    if (lane == 0) ws[w] = s;
    __syncthreads();
    if (t == 0) partial[seg * MAXNB + blockIdx.x] = ws[0] + ws[1] + ws[2] + ws[3];
}

__global__ void scan_base(int* __restrict__ partial, int nA, int nB, int nC,
                          int* __restrict__ offA, int* __restrict__ offB, int* __restrict__ offC)
{
    const int seg = threadIdx.x;
    if (seg >= 3) return;
    const int n = seg == 0 ? nA : (seg == 1 ? nB : nC);
    int* off = seg == 0 ? offA : (seg == 1 ? offB : offC);
    const int nb = (n + SCH - 1) / SCH;
    int run = 0;
    for (int b = 0; b < nb; ++b) {
        const int v = partial[seg * MAXNB + b];
        partial[seg * MAXNB + b] = run;
        run += v;
    }
    off[n] = run;
}

__global__ __launch_bounds__(256) void scan_final(
    int* __restrict__ c0, int nA, int* __restrict__ offA,
    int* __restrict__ c1, int nB, int* __restrict__ offB,
    int* __restrict__ c2, int nC, int* __restrict__ offC,
    const int* __restrict__ partial)
{
    const int seg = blockIdx.y;
    int* c = seg == 0 ? c0 : (seg == 1 ? c1 : c2);
    int* off = seg == 0 ? offA : (seg == 1 ? offB : offC);
    const int n = seg == 0 ? nA : (seg == 1 ? nB : nC);
    const int beg = blockIdx.x * SCH;
    if (beg >= n) return;
    const int t = threadIdx.x, lane = t & 63, w = t >> 6;
    const int base_i = beg + t * 8;

    int v[8];
    int run = 0;
#pragma unroll
    for (int j = 0; j < 8; ++j) {
        const int i = base_i + j;
        const int x = (i < n) ? c[i] : 0;
        v[j] = run;
        run += x;
    }
    const int tsum = run;
    int x = tsum;
#pragma unroll
    for (int o = 1; o < 64; o <<= 1) {
        const int y = __shfl_up(x, o);
        if (lane >= o) x += y;
    }
    const int wexc = x - tsum;
    __shared__ int wsum[4];
    if (lane == 63) wsum[w] = x;
    __syncthreads();
    int wbase = 0;
    for (int i = 0; i < w; ++i) wbase += wsum[i];
    const int base = partial[seg * MAXNB + blockIdx.x] + wbase + wexc;
#pragma unroll
    for (int j = 0; j < 8; ++j) {
        const int i = base_i + j;
        if (i < n) {
            const int e = base + v[j];
            off[i] = e;
            c[i] = e;
        }
    }
}

// scatter: one int2{src, ev} store per edge, fused over etypes
__global__ void scatter3(const int* __restrict__ d0, const int* __restrict__ s0,
                         const float* __restrict__ e0, int E0, int* __restrict__ p0, int2* __restrict__ g0,
                         const int* __restrict__ d1, const int* __restrict__ s1,
                         const float* __restrict__ e1, int E1, int* __restrict__ p1, int2* __restrict__ g1,
                         const int* __restrict__ d2, const int* __restrict__ s2,
                         const float* __restrict__ e2, int E2, int* __restrict__ p2, int2* __restrict__ g2)
{
    const int seg = blockIdx.y;
    const int* dst = seg == 0 ? d0 : (seg == 1 ? d1 : d2);
    const int* src = seg == 0 ? s0 : (seg == 1 ? s1 : s2);
    const float* ev = seg == 0 ? e0 : (seg == 1 ? e1 : e2);
    int* pos = seg == 0 ? p0 : (seg == 1 ? p1 : p2);
    int2* edg = seg == 0 ? g0 : (seg == 1 ? g1 : g2);
    const int E = seg == 0 ? E0 : (seg == 1 ? E1 : E2);
    for (int i = blockIdx.x * blockDim.x + threadIdx.x; i < E; i += gridDim.x * blockDim.x) {
        const int d = dst[i];
        const int p = atomicAdd(&pos[d], 1);
        edg[p] = make_int2(src[i], __float_as_int(ev[i]));
    }
}

// ---------------- edge aggregation v3: fused 3 etypes, 2 dsts/wave, no-max exp2 ----------------
__global__ __launch_bounds__(256) void edge_agg3(
    const int* __restrict__ off0, const int2* __restrict__ edg0,
    const unsigned short* __restrict__ K0e, const unsigned short* __restrict__ Q0e,
    const unsigned short* __restrict__ V0e, unsigned short* __restrict__ out0, int nd0,
    const int* __restrict__ off1, const int2* __restrict__ edg1,
    const unsigned short* __restrict__ K1e, const unsigned short* __restrict__ Q1e,
    const unsigned short* __restrict__ V1e, unsigned short* __restrict__ out1, int nd1,
    const int* __restrict__ off2, const int2* __restrict__ edg2,
    const unsigned short* __restrict__ K2e, const unsigned short* __restrict__ Q2e,
    const unsigned short* __restrict__ V2e, unsigned short* __restrict__ out2, int nd2,
    const float* __restrict__ ew, const float* __restrict__ eb)
{
    const int seg = blockIdx.y;
    const int* off = seg == 0 ? off0 : (seg == 1 ? off1 : off2);
    const int2* edg = seg == 0 ? edg0 : (seg == 1 ? edg1 : edg2);
    const unsigned short* K = seg == 0 ? K0e : (seg == 1 ? K1e : K2e);
    const unsigned short* Q = seg == 0 ? Q0e : (seg == 1 ? Q1e : Q2e);
    const unsigned short* V = seg == 0 ? V0e : (seg == 1 ? V1e : V2e);
    unsigned short* aggb = seg == 0 ? out0 : (seg == 1 ? out1 : out2);
    const int n_dst = seg == 0 ? nd0 : (seg == 1 ? nd1 : nd2);

    const int wv = (blockIdx.x * blockDim.x + threadIdx.x) >> 6;
    const int lane = threadIdx.x & 63;
    const int half = lane >> 5, l5 = lane & 31;
    const int dst = 2 * wv + half;
    const bool valid = dst < n_dst;
    int beg = 0, len = 0;
    if (valid) { beg = off[dst]; len = off[dst + 1] - beg; }
    const int maxLen = max(len, __shfl_xor(len, 32));
    if (maxLen == 0) {
        if (valid) *(ushort4*)(aggb + (size_t)dst * NDIM + 4 * l5) = (ushort4){0, 0, 0, 0};
        return;
    }
    const float LOG2E = 1.4426950408889634f;
    const float ews = ew[0] * 0.25f * LOG2E;
    const float ebs = eb[0] * 0.25f * LOG2E;
    float qx = 0.f, qy = 0.f, qz = 0.f, qw = 0.f;
    if (valid) {
        const ushort4 qr = *(const ushort4*)(Q + (size_t)dst * NDIM + 4 * l5);
        qx = bf2f(qr.x); qy = bf2f(qr.y); qz = bf2f(qr.z); qw = bf2f(qr.w);
    }
    float z = 0.f, a0 = 0.f, a1 = 0.f, a2 = 0.f, a3 = 0.f;

    // chunked coalesced (src,ev) prefetch; broadcast via shfl inside the chunk
    int2 ec = (l5 < len) ? edg[beg + l5] : make_int2(0, 0);
    for (int t0 = 0; t0 < maxLen; t0 += 32) {
        int2 en = make_int2(0, 0);
        const int t0n = t0 + 32;
        if (t0n < maxLen && t0n + l5 < len) en = edg[beg + t0n + l5];
        const int lim = min(32, maxLen - t0);
        for (int u = 0; u < lim; ++u) {
            const int sl = (half << 5) + u;
            const int s = __shfl(ec.x, sl);
            const float fv = __int_as_float(__shfl(ec.y, sl));
            const bool act = (t0 + u) < len;
            const ushort4 kr = *(const ushort4*)(K + (size_t)s * NDIM + 4 * l5);
            const ushort4 vr = *(const ushort4*)(V + (size_t)s * NDIM + 4 * l5);
            float d = qx * bf2f(kr.x) + qy * bf2f(kr.y) + qz * bf2f(kr.z) + qw * bf2f(kr.w);
            d += __shfl_xor(d, 1);
            d += __shfl_xor(d, 2);
            const float p = act ? exp2f(d * (fv * ews + ebs)) : 0.f;   // no-max softmax (scores bounded)
            z += p;
            a0 += p * bf2f(vr.x);
            a1 += p * bf2f(vr.y);
            a2 += p * bf2f(vr.z);
            a3 += p * bf2f(vr.w);
        }
        ec = en;
    }
    if (valid) {
        const float inv = (len > 0) ? 1.f / z : 0.f;
        ushort4 o;
        o.x = f2bf(a0 * inv); o.y = f2bf(a1 * inv);
        o.z = f2bf(a2 * inv); o.w = f2bf(a3 * inv);
        *(ushort4*)(aggb + (size_t)dst * NDIM + 4 * l5) = o;
    }
}

extern "C" void kernel_launch(void* const* d_in, const int* in_sizes, int n_in,
                              void* d_out, int out_size, void* d_ws, size_t ws_size,
                              hipStream_t stream)
{
    const float* feat0 = (const float*)d_in[0];
    const float* feat1 = (const float*)d_in[1];
    const float* ev0 = (const float*)d_in[2];
    const float* ev1 = (const float*)d_in[3];
    const float* ev2 = (const float*)d_in[4];
    const int* src0 = (const int*)d_in[5];
    const int* dst0 = (const int*)d_in[6];
    const int* src1 = (const int*)d_in[7];
    const int* dst1 = (const int*)d_in[8];
    const int* src2 = (const int*)d_in[9];
    const int* dst2 = (const int*)d_in[10];
    const float* Kw = (const float*)d_in[11];
    const float* Kb = (const float*)d_in[12];
    const float* Qw = (const float*)d_in[13];
    const float* Qb = (const float*)d_in[14];
    const float* Vw = (const float*)d_in[15];
    const float* Vb = (const float*)d_in[16];
    const float* Aw = (const float*)d_in[17];
    const float* Ab = (const float*)d_in[18];
    const float* ew = (const float*)d_in[19];
    const float* eb = (const float*)d_in[20];
    const float* skip = (const float*)d_in[21];

    const int n0 = in_sizes[0] / NDIM;
    const int n1 = in_sizes[1] / NDIM;
    const int E0 = in_sizes[5];
    const int E1 = in_sizes[7];
    const int E2 = in_sizes[9];

    auto rup = [](size_t b) { return (b + 255) & ~size_t(255); };
    const size_t need =
        rup((size_t)8 * 16384 * 2) +
        rup((size_t)n0 * NDIM * 2) * 3 +
        rup((size_t)n1 * NDIM * 2) * 3 +
        rup((size_t)n1 * NDIM * 2) +
        rup((size_t)n0 * NDIM * 2) * 2 +
        rup((size_t)(n1 + 1) * 4) +
        rup((size_t)(n0 + 1) * 4) * 2 +
        rup((size_t)(n1 + n0 + n0) * 4) +
        rup((size_t)3 * MAXNB * 4) +
        rup((size_t)E0 * 8) + rup((size_t)E1 * 8) + rup((size_t)E2 * 8);
    if (ws_size < need) return;

    char* p = (char*)d_ws;
    auto alloc = [&](size_t bytes) -> char* {
        char* r = p;
        p += (bytes + 255) & ~size_t(255);
        return r;
    };
    unsigned short* Wtbuf = (unsigned short*)alloc((size_t)8 * 16384 * 2);
    unsigned short* K0 = (unsigned short*)alloc((size_t)n0 * NDIM * 2);
    unsigned short* Q0 = (unsigned short*)alloc((size_t)n0 * NDIM * 2);
    unsigned short* V0 = (unsigned short*)alloc((size_t)n0 * NDIM * 2);
    unsigned short* K1 = (unsigned short*)alloc((size_t)n1 * NDIM * 2);
    unsigned short* Q1 = (unsigned short*)alloc((size_t)n1 * NDIM * 2);
    unsigned short* V1 = (unsigned short*)alloc((size_t)n1 * NDIM * 2);
    unsigned short* aggb1  = (unsigned short*)alloc((size_t)n1 * NDIM * 2);
    unsigned short* aggb0a = (unsigned short*)alloc((size_t)n0 * NDIM * 2);
    unsigned short* aggb0b = (unsigned short*)alloc((size_t)n0 * NDIM * 2);
    int* off0 = (int*)alloc((size_t)(n1 + 1) * 4);
    int* off1 = (int*)alloc((size_t)(n0 + 1) * 4);
    int* off2 = (int*)alloc((size_t)(n0 + 1) * 4);
    int* posA = (int*)alloc((size_t)(n1 + n0 + n0) * 4);
    int* pos0 = posA;
    int* pos1 = posA + n1;
    int* pos2 = posA + n1 + n0;
    int* partial = (int*)alloc((size_t)3 * MAXNB * 4);
    int2* edg0 = (int2*)alloc((size_t)E0 * 8);
    int2* edg1 = (int2*)alloc((size_t)E1 * 8);
    int2* edg2 = (int2*)alloc((size_t)E2 * 8);

    dim3 blk(256);
    dim3 g0((n0 + 63) / 64), g1((n1 + 63) / 64);

    wt_prep<<<8, 256, 0, stream>>>(Kw, Qw, Vw, Aw, Wtbuf);
    gemm_kqv<<<g0, blk, 0, stream>>>(feat0, Wtbuf,             Kb,        Qb,        Vb,        K0, Q0, V0, n0);
    gemm_kqv<<<g1, blk, 0, stream>>>(feat1, Wtbuf + 4 * 16384, Kb + NDIM, Qb + NDIM, Vb + NDIM, K1, Q1, V1, n1);

    hipMemsetAsync(posA, 0, (size_t)(n1 + n0 + n0) * 4, stream);
    hist3<<<dim3(1024, 3), blk, 0, stream>>>(dst0, E0, pos0, dst1, E1, pos1, dst2, E2, pos2);

    const int nmax = (n0 > n1) ? n0 : n1;
    const int nb = (nmax + SCH - 1) / SCH;
    scan_partial<<<dim3(nb, 3), blk, 0, stream>>>(pos0, n1, pos1, n0, pos2, n0, partial);
    scan_base<<<1, 64, 0, stream>>>(partial, n1, n0, n0, off0, off1, off2);
    scan_final<<<dim3(nb, 3), blk, 0, stream>>>(pos0, n1, off0, pos1, n0, off1, pos2, n0, off2, partial);

    scatter3<<<dim3(1024, 3), blk, 0, stream>>>(dst0, src0, ev0, E0, pos0, edg0,
                                                dst1, src1, ev1, E1, pos1, edg1,
                                                dst2, src2, ev2, E2, pos2, edg2);

    const int ebx = ((nmax + 1) / 2 + 3) / 4;
    edge_agg3<<<dim3(ebx, 3), blk, 0, stream>>>(
        off0, edg0, K0, Q1, V0, aggb1, n1,
        off1, edg1, K1, Q0, V1, aggb0a, n0,
        off2, edg2, K0, Q0, V0, aggb0b, n0,
        ew, eb);

    float* out = (float*)d_out;
    gemm_out2<true ><<<g0, blk, 0, stream>>>(aggb0a, aggb0b, Wtbuf + 3 * 16384, Ab,        feat0, skip, 0, out, n0);
    gemm_out2<false><<<g1, blk, 0, stream>>>(aggb1,  nullptr, Wtbuf + 7 * 16384, Ab + NDIM, feat1, skip, 1, out + (size_t)n0 * NDIM, n1);
}